// Round 7
// baseline (238.219 us; speedup 1.0000x reference)
//
#include <hip/hip_runtime.h>
#include <hip/hip_cooperative_groups.h>

namespace cg = cooperative_groups;

#define NBLK 1024   // encoder grid; partials live at ws[1024 .. 1024+NBLK*64)

// ws float layout: [0..127] z | [128..639] ghh | [640..767] hnew |
// [768..831] zp1 | [840..903] feat | [1024..] encoder partials (or gmax[64])
#define WS_Z    0
#define WS_GHH  128
#define WS_HNEW 640
#define WS_ZP1  768
#define WS_FEAT 840
#define WS_PART 1024

typedef __attribute__((ext_vector_type(8))) short bf16x8;
typedef __attribute__((ext_vector_type(4))) float f32x4;

union U4 { unsigned int u[4]; bf16x8 v; };

static __device__ __forceinline__ unsigned int pack_bf16(float lo, float hi) {
    return (__float_as_uint(hi) & 0xFFFF0000u) | (__float_as_uint(lo) >> 16);
}

// ---------------- atomic-mode prologue (only if ws too small) ----------------
__global__ __launch_bounds__(64) void prep_kernel(unsigned int* __restrict__ g)
{
    g[threadIdx.x & 63] = 0u;   // below encode(-inf)=0x007FFFFF
}

// ---------- encoder: per-point MLP 2->16->32->64 via MFMA, channel max ----------
// (identical to R6 except partials/gmax base moved to ws+1024)
__global__ __launch_bounds__(256) void encoder_kernel(
    const float* __restrict__ x,
    const float* __restrict__ c1w, const float* __restrict__ c1b,
    const float* __restrict__ c2w, const float* __restrict__ c2b,
    const float* __restrict__ c3w,
    float* __restrict__ ws, int N, int use_atomic)
{
    __shared__ float sW1x[16], sW1y[16], sB1s[16];
    __shared__ float sW2[512], sB2[32];
    __shared__ float sW3[2048];
    __shared__ unsigned int sh2[4 * 272];
    __shared__ float wred[4 * 64];

    int t = threadIdx.x;
    if (t < 16) { sW1x[t] = c1w[2 * t]; sW1y[t] = c1w[2 * t + 1]; sB1s[t] = c1b[t]; }
    if (t < 32) sB2[t] = c2b[t];
    for (int i = t; i < 512; i += 256)  sW2[i] = c2w[i];
    for (int i = t; i < 2048; i += 256) sW3[i] = c3w[i];
    __syncthreads();

    const int lane = t & 63, wid = t >> 6;
    const int n16 = lane & 15, q = lane >> 4;

    bf16x8 a2[2];
#pragma unroll
    for (int tt = 0; tt < 2; ++tt)
#pragma unroll
        for (int j = 0; j < 8; ++j) {
            int k = q * 8 + j;
            float w = (k < 16) ? sW2[(tt * 16 + n16) * 16 + k] : 0.0f;
            a2[tt][j] = (short)(__float_as_uint(w) >> 16);
        }
    bf16x8 a3[4];
#pragma unroll
    for (int tt = 0; tt < 4; ++tt)
#pragma unroll
        for (int j = 0; j < 8; ++j) {
            float w = sW3[(tt * 16 + n16) * 32 + q * 8 + j];
            a3[tt][j] = (short)(__float_as_uint(w) >> 16);
        }
    float w1x[8], w1y[8], b1v[8];
#pragma unroll
    for (int j = 0; j < 8; ++j) {
        int k = q * 8 + j;
        if (k < 16) { w1x[j] = sW1x[k]; w1y[j] = sW1y[k]; b1v[j] = sB1s[k]; }
        else        { w1x[j] = 0.f;     w1y[j] = 0.f;     b1v[j] = 0.f; }
    }
    float b2a[4], b2b[4];
#pragma unroll
    for (int r = 0; r < 4; ++r) { b2a[r] = sB2[q * 4 + r]; b2b[r] = sB2[16 + q * 4 + r]; }

    float vmax[16];
#pragma unroll
    for (int i = 0; i < 16; ++i) vmax[i] = -INFINITY;

    unsigned int* hb = sh2 + wid * 272;
    const int WPG = NBLK * 4;
    const int gw = blockIdx.x * 4 + wid;
    const int niter = (N + WPG * 16 - 1) / (WPG * 16);

    int p = gw * 16 + n16; if (p >= N) p = N - 1;
    float px = x[3 + p], py = x[3 + N + p];

#pragma unroll 1
    for (int it = 0; it < niter; ++it) {
        float cpx = px, cpy = py;
        if (it + 1 < niter) {
            int pn = ((it + 1) * WPG + gw) * 16 + n16;
            if (pn >= N) pn = N - 1;
            px = x[3 + pn]; py = x[3 + N + pn];
        }

        unsigned int h1d0 = 0, h1d1 = 0, h1d2 = 0, h1d3 = 0;
        if (q < 2) {
            float h0 = fmaxf(fmaf(w1x[0], cpx, fmaf(w1y[0], cpy, b1v[0])), 0.f);
            float h1 = fmaxf(fmaf(w1x[1], cpx, fmaf(w1y[1], cpy, b1v[1])), 0.f);
            float h2 = fmaxf(fmaf(w1x[2], cpx, fmaf(w1y[2], cpy, b1v[2])), 0.f);
            float h3 = fmaxf(fmaf(w1x[3], cpx, fmaf(w1y[3], cpy, b1v[3])), 0.f);
            float h4 = fmaxf(fmaf(w1x[4], cpx, fmaf(w1y[4], cpy, b1v[4])), 0.f);
            float h5 = fmaxf(fmaf(w1x[5], cpx, fmaf(w1y[5], cpy, b1v[5])), 0.f);
            float h6 = fmaxf(fmaf(w1x[6], cpx, fmaf(w1y[6], cpy, b1v[6])), 0.f);
            float h7 = fmaxf(fmaf(w1x[7], cpx, fmaf(w1y[7], cpy, b1v[7])), 0.f);
            h1d0 = pack_bf16(h0, h1); h1d1 = pack_bf16(h2, h3);
            h1d2 = pack_bf16(h4, h5); h1d3 = pack_bf16(h6, h7);
        }
        U4 bu; bu.u[0] = h1d0; bu.u[1] = h1d1; bu.u[2] = h1d2; bu.u[3] = h1d3;

        f32x4 z4 = {0.f, 0.f, 0.f, 0.f};
        f32x4 acc2a = __builtin_amdgcn_mfma_f32_16x16x32_bf16(a2[0], bu.v, z4, 0, 0, 0);
        f32x4 acc2b = __builtin_amdgcn_mfma_f32_16x16x32_bf16(a2[1], bu.v, z4, 0, 0, 0);

        unsigned int base = (unsigned int)(n16 * 17);
        hb[base + 2 * q]     = pack_bf16(fmaxf(acc2a[0] + b2a[0], 0.f),
                                         fmaxf(acc2a[1] + b2a[1], 0.f));
        hb[base + 2 * q + 1] = pack_bf16(fmaxf(acc2a[2] + b2a[2], 0.f),
                                         fmaxf(acc2a[3] + b2a[3], 0.f));
        hb[base + 8 + 2 * q] = pack_bf16(fmaxf(acc2b[0] + b2b[0], 0.f),
                                         fmaxf(acc2b[1] + b2b[1], 0.f));
        hb[base + 9 + 2 * q] = pack_bf16(fmaxf(acc2b[2] + b2b[2], 0.f),
                                         fmaxf(acc2b[3] + b2b[3], 0.f));
        __builtin_amdgcn_s_waitcnt(0xc07f);
        U4 ru;
        ru.u[0] = hb[base + 4 * q];     ru.u[1] = hb[base + 4 * q + 1];
        ru.u[2] = hb[base + 4 * q + 2]; ru.u[3] = hb[base + 4 * q + 3];

        f32x4 o0 = __builtin_amdgcn_mfma_f32_16x16x32_bf16(a3[0], ru.v, z4, 0, 0, 0);
        f32x4 o1 = __builtin_amdgcn_mfma_f32_16x16x32_bf16(a3[1], ru.v, z4, 0, 0, 0);
        f32x4 o2 = __builtin_amdgcn_mfma_f32_16x16x32_bf16(a3[2], ru.v, z4, 0, 0, 0);
        f32x4 o3 = __builtin_amdgcn_mfma_f32_16x16x32_bf16(a3[3], ru.v, z4, 0, 0, 0);
#pragma unroll
        for (int r = 0; r < 4; ++r) {
            vmax[r]      = fmaxf(vmax[r],      o0[r]);
            vmax[4 + r]  = fmaxf(vmax[4 + r],  o1[r]);
            vmax[8 + r]  = fmaxf(vmax[8 + r],  o2[r]);
            vmax[12 + r] = fmaxf(vmax[12 + r], o3[r]);
        }
    }

#pragma unroll
    for (int i = 0; i < 16; ++i) {
        float v = vmax[i];
        v = fmaxf(v, __shfl_xor(v, 1, 64));
        v = fmaxf(v, __shfl_xor(v, 2, 64));
        v = fmaxf(v, __shfl_xor(v, 4, 64));
        v = fmaxf(v, __shfl_xor(v, 8, 64));
        vmax[i] = v;
    }
    if (n16 == 0) {
#pragma unroll
        for (int tt = 0; tt < 4; ++tt)
#pragma unroll
            for (int r = 0; r < 4; ++r)
                wred[wid * 64 + tt * 16 + q * 4 + r] = vmax[tt * 4 + r];
    }
    __syncthreads();
    if (t < 64) {
        float m = fmaxf(fmaxf(wred[t], wred[64 + t]),
                        fmaxf(wred[128 + t], wred[192 + t]));
        if (use_atomic) {
            unsigned int b = __float_as_uint(m);
            unsigned int e = (b & 0x80000000u) ? ~b : (b | 0x80000000u);
            atomicMax((unsigned int*)ws + WS_PART + t, e);
        } else {
            ws[WS_PART + blockIdx.x * 64 + t] = m;
        }
    }
}

// ---------- cooperative tail: 17 blocks x 256 ----------
struct TailArgs {
    const float *x, *hx, *cx, *c3b, *fcw, *fcb, *o1w, *o1b, *o2w, *o2b,
                *pw, *pb, *wih, *whh, *bih, *bhh, *q1w, *q1b, *q2w, *q2b,
                *aw1, *ab1, *aw2, *ab2, *ciw1, *cib1, *ciw2, *cib2,
                *cew1, *ceb1, *cew2, *ceb2;
    float* ws; float* out; int use_atomic;
};

__global__ __launch_bounds__(256) void coop_tail(TailArgs a)
{
    cg::grid_group grid = cg::this_grid();
    const int b = blockIdx.x, t = threadIdx.x;
    __shared__ float shx[128], zL[128], hnL[128];
    __shared__ float featL[64], obsL[64], zp1L[64], zp2L[64];
    __shared__ float lg[32], poseL[8], sig8L[8], odomL[3];
    __shared__ float a1s[16], cih[16], ceh[16], logits[5];

    const int rl = t >> 3, sub = t & 7;          // 32 rows x 8 threads
    const int C0 = (b - 1) * 8;                  // cells for worker blocks
    const int gr = (rl >> 3) * 128 + C0 + (rl & 7);  // gate row (i,f,g,o major)
    float4 wr0, wr1, wr2, wr3;                   // wih preload (P1->P2)

    // ---------------- P0: pose (b0) | ghh + feat reduce (b1..16) ----------------
    if (b == 0) {
        if (t < 3) odomL[t] = a.x[t];
        __syncthreads();
        if (t < 8) {
            float s = a.o1b[t];
            for (int k = 0; k < 3; k++) s = fmaf(a.o1w[t * 3 + k], odomL[k], s);
            sig8L[t] = 1.0f / (1.0f + expf(-s));
        }
        __syncthreads();
        if (t < 8) {
            float s = a.o2b[t];
            for (int k = 0; k < 8; k++) s = fmaf(a.o2w[t * 8 + k], sig8L[k], s);
            poseL[t] = fmaxf(s, 0.0f);
            a.out[263 + t] = poseL[t];
        }
    } else {
        if (t < 128) shx[t] = a.hx[t];
        __syncthreads();
        const float4* w4 = (const float4*)(a.whh + (size_t)gr * 128) + sub * 4;
        float s = 0.0f;
#pragma unroll
        for (int j = 0; j < 4; j++) {
            float4 w = w4[j];
            int k = sub * 16 + 4 * j;
            s = fmaf(w.x, shx[k], fmaf(w.y, shx[k + 1],
                fmaf(w.z, shx[k + 2], fmaf(w.w, shx[k + 3], s))));
        }
        s += __shfl_xor(s, 1, 64); s += __shfl_xor(s, 2, 64); s += __shfl_xor(s, 4, 64);
        if (sub == 0) a.ws[WS_GHH + gr] = a.bhh[gr] + s;

        if (!a.use_atomic) {
            int w = t >> 6, lane = t & 63;
            int c = (b - 1) * 4 + w;
            float m = -INFINITY;
            const float* part = a.ws + WS_PART;
#pragma unroll 4
            for (int j = 0; j < NBLK / 64; j++)
                m = fmaxf(m, part[(lane * (NBLK / 64) + j) * 64 + c]);
#pragma unroll
            for (int off = 32; off > 0; off >>= 1)
                m = fmaxf(m, __shfl_xor(m, off, 64));
            if (lane == 0) a.ws[WS_FEAT + c] = fmaxf(m + a.c3b[c], 0.0f);
        } else if (b == 1 && t < 64) {
            unsigned int u = ((unsigned int*)a.ws)[WS_PART + t];
            unsigned int bb = (u & 0x80000000u) ? (u ^ 0x80000000u) : ~u;
            a.ws[WS_FEAT + t] = fmaxf(__uint_as_float(bb) + a.c3b[t], 0.0f);
        }
    }
    __threadfence();
    grid.sync();

    // ---------------- P1: obs + z (b0) | wih register preload (b1..16) ----------
    if (b == 0) {
        if (t < 64) featL[t] = a.ws[WS_FEAT + t];
        __syncthreads();
        if (t < 64) {
            float s = a.fcb[t];
            const float4* f4 = (const float4*)(a.fcw + (size_t)t * 64);
            for (int qq = 0; qq < 16; qq++) {
                float4 w = f4[qq];
                s = fmaf(w.x, featL[4 * qq], fmaf(w.y, featL[4 * qq + 1],
                    fmaf(w.z, featL[4 * qq + 2], fmaf(w.w, featL[4 * qq + 3], s))));
            }
            obsL[t] = s;
        }
        __syncthreads();
        if (t < 128) {
            float s = a.pb[t];
            const float4* p4 = (const float4*)(a.pw + (size_t)t * 72);
            for (int qq = 0; qq < 16; qq++) {
                float4 w = p4[qq];
                s = fmaf(w.x, obsL[4 * qq], fmaf(w.y, obsL[4 * qq + 1],
                    fmaf(w.z, obsL[4 * qq + 2], fmaf(w.w, obsL[4 * qq + 3], s))));
            }
            float4 w16 = p4[16], w17 = p4[17];
            s = fmaf(w16.x, poseL[0], fmaf(w16.y, poseL[1],
                fmaf(w16.z, poseL[2], fmaf(w16.w, poseL[3], s))));
            s = fmaf(w17.x, poseL[4], fmaf(w17.y, poseL[5],
                fmaf(w17.z, poseL[6], fmaf(w17.w, poseL[7], s))));
            a.ws[WS_Z + t] = fmaxf(s, 0.0f);
        }
    } else {
        const float4* w4 = (const float4*)(a.wih + (size_t)gr * 128) + sub * 4;
        wr0 = w4[0]; wr1 = w4[1]; wr2 = w4[2]; wr3 = w4[3];
    }
    __threadfence();
    grid.sync();

    // ---------------- P2: gates + LSTM update (b1..16) ----------------
    if (b > 0) {
        if (t < 128) zL[t] = a.ws[WS_Z + t];
        __syncthreads();
        int k = sub * 16;
        float s;
        s = fmaf(wr0.x, zL[k], fmaf(wr0.y, zL[k + 1],
            fmaf(wr0.z, zL[k + 2], fmaf(wr0.w, zL[k + 3], 0.0f))));
        s = fmaf(wr1.x, zL[k + 4], fmaf(wr1.y, zL[k + 5],
            fmaf(wr1.z, zL[k + 6], fmaf(wr1.w, zL[k + 7], s))));
        s = fmaf(wr2.x, zL[k + 8], fmaf(wr2.y, zL[k + 9],
            fmaf(wr2.z, zL[k + 10], fmaf(wr2.w, zL[k + 11], s))));
        s = fmaf(wr3.x, zL[k + 12], fmaf(wr3.y, zL[k + 13],
            fmaf(wr3.z, zL[k + 14], fmaf(wr3.w, zL[k + 15], s))));
        s += __shfl_xor(s, 1, 64); s += __shfl_xor(s, 2, 64); s += __shfl_xor(s, 4, 64);
        if (sub == 0) lg[rl] = a.ws[WS_GHH + gr] + a.bih[gr] + s;
        __syncthreads();
        if (t < 8) {
            int c = C0 + t;
            float gI = lg[t], gF = lg[8 + t], gG = lg[16 + t], gO = lg[24 + t];
            float ig = 1.0f / (1.0f + expf(-gI));
            float fg = 1.0f / (1.0f + expf(-gF));
            float gg = tanhf(gG);
            float og = 1.0f / (1.0f + expf(-gO));
            float cn = fg * a.cx[c] + ig * gg;
            float hn = og * tanhf(cn);
            a.out[7 + c] = hn;
            a.out[135 + c] = cn;
            a.ws[WS_HNEW + c] = hn;
        }
    }
    __threadfence();
    grid.sync();

    // ---------------- P3: zp1 rows (b1..16, 4 rows each) ----------------
    if (b > 0) {
        if (t < 128) hnL[t] = a.ws[WS_HNEW + t];
        __syncthreads();
        int w = t >> 6, lane = t & 63;
        int rr = (b - 1) * 4 + w;
        float s = fmaf(a.q1w[(size_t)rr * 128 + 2 * lane], hnL[2 * lane],
                       a.q1w[(size_t)rr * 128 + 2 * lane + 1] * hnL[2 * lane + 1]);
#pragma unroll
        for (int off = 32; off > 0; off >>= 1) s += __shfl_xor(s, off, 64);
        if (lane == 0) a.ws[WS_ZP1 + rr] = fmaxf(s + a.q1b[rr], 0.0f);
    }
    __threadfence();
    grid.sync();

    // ---------------- P4: zp2 + heads + softmax (b0) ----------------
    if (b == 0) {
        if (t < 64) zp1L[t] = a.ws[WS_ZP1 + t];
        __syncthreads();
        if (t < 64) {
            float s = a.q2b[t];
            const float4* q4 = (const float4*)(a.q2w + (size_t)t * 64);
            for (int qq = 0; qq < 16; qq++) {
                float4 w = q4[qq];
                s = fmaf(w.x, zp1L[4 * qq], fmaf(w.y, zp1L[4 * qq + 1],
                    fmaf(w.z, zp1L[4 * qq + 2], fmaf(w.w, zp1L[4 * qq + 3], s))));
            }
            zp2L[t] = fmaxf(s, 0.0f);
        }
        __syncthreads();
        if (t < 16) {
            float s = a.ab1[t];
            for (int k = 0; k < 64; k++) s = fmaf(a.aw1[t * 64 + k], zp2L[k], s);
            a1s[t] = fmaxf(s, 0.0f);
        } else if (t < 32) {
            int r = t - 16;
            float s = a.cib1[r];
            for (int k = 0; k < 64; k++) s = fmaf(a.ciw1[r * 64 + k], zp2L[k], s);
            cih[r] = fmaxf(s, 0.0f);
        } else if (t < 48) {
            int r = t - 32;
            float s = a.ceb1[r];
            for (int k = 0; k < 64; k++) s = fmaf(a.cew1[r * 64 + k], zp2L[k], s);
            ceh[r] = fmaxf(s, 0.0f);
        }
        __syncthreads();
        if (t < 5) {
            float s = a.ab2[t];
            for (int k = 0; k < 16; k++) s = fmaf(a.aw2[t * 16 + k], a1s[k], s);
            logits[t] = s;
        } else if (t == 5) {
            float s = a.cib2[0];
            for (int k = 0; k < 16; k++) s = fmaf(a.ciw2[k], cih[k], s);
            a.out[5] = s;
        } else if (t == 6) {
            float s = a.ceb2[0];
            for (int k = 0; k < 16; k++) s = fmaf(a.cew2[k], ceh[k], s);
            a.out[6] = s;
        }
        __syncthreads();
        if (t == 0) {
            float m = logits[0];
            for (int i = 1; i < 5; i++) m = fmaxf(m, logits[i]);
            float e[5], s = 0.0f;
            for (int i = 0; i < 5; i++) { e[i] = expf(logits[i] - m); s += e[i]; }
            for (int i = 0; i < 5; i++) a.out[i] = e[i] / s;
        }
    }
}

extern "C" void kernel_launch(void* const* d_in, const int* in_sizes, int n_in,
                              void* d_out, int out_size, void* d_ws, size_t ws_size,
                              hipStream_t stream)
{
    const float* x    = (const float*)d_in[0];
    const float* c1w  = (const float*)d_in[3];
    const float* c1b  = (const float*)d_in[4];
    const float* c2w  = (const float*)d_in[5];
    const float* c2b  = (const float*)d_in[6];
    const float* c3w  = (const float*)d_in[7];

    int N = (in_sizes[0] - 3) / 2;
    size_t need = (size_t)(1024 + NBLK * 64) * 4;
    int use_atomic = (ws_size < need) ? 1 : 0;

    if (use_atomic)
        prep_kernel<<<1, 64, 0, stream>>>((unsigned int*)d_ws + WS_PART);
    encoder_kernel<<<NBLK, 256, 0, stream>>>(x, c1w, c1b, c2w, c2b, c3w,
                                             (float*)d_ws, N, use_atomic);

    TailArgs a;
    a.x = x;
    a.hx  = (const float*)d_in[1];  a.cx   = (const float*)d_in[2];
    a.c3b = (const float*)d_in[8];
    a.fcw = (const float*)d_in[9];  a.fcb  = (const float*)d_in[10];
    a.o1w = (const float*)d_in[11]; a.o1b  = (const float*)d_in[12];
    a.o2w = (const float*)d_in[13]; a.o2b  = (const float*)d_in[14];
    a.pw  = (const float*)d_in[15]; a.pb   = (const float*)d_in[16];
    a.wih = (const float*)d_in[17]; a.whh  = (const float*)d_in[18];
    a.bih = (const float*)d_in[19]; a.bhh  = (const float*)d_in[20];
    a.q1w = (const float*)d_in[21]; a.q1b  = (const float*)d_in[22];
    a.q2w = (const float*)d_in[23]; a.q2b  = (const float*)d_in[24];
    a.aw1 = (const float*)d_in[25]; a.ab1  = (const float*)d_in[26];
    a.aw2 = (const float*)d_in[27]; a.ab2  = (const float*)d_in[28];
    a.ciw1 = (const float*)d_in[29]; a.cib1 = (const float*)d_in[30];
    a.ciw2 = (const float*)d_in[31]; a.cib2 = (const float*)d_in[32];
    a.cew1 = (const float*)d_in[33]; a.ceb1 = (const float*)d_in[34];
    a.cew2 = (const float*)d_in[35]; a.ceb2 = (const float*)d_in[36];
    a.ws = (float*)d_ws; a.out = (float*)d_out; a.use_atomic = use_atomic;

    void* kargs[] = { (void*)&a };
    hipLaunchCooperativeKernel((const void*)coop_tail, dim3(17), dim3(256),
                               kargs, 0, stream);
}

// Round 8
// 160.802 us; speedup vs baseline: 1.4814x; 1.4814x over previous
//
#include <hip/hip_runtime.h>

#define NBLK 1024   // encoder grid; partials live at ws[1024 .. 1024+NBLK*64)

// ws float layout:
#define WS_Z    0      // [0..127]   z
#define WS_GHH  128    // [128..639] whh@hx + bhh
#define WS_HNEW 640    // [640..767] h_new
#define WS_ZP1  768    // [768..831] zp1
#define WS_FEAT 840    // [840..903] feat (post bias+relu)
#define WS_POSE 904    // [904..911] pose
#define WS_OBS  912    // [912..975] obs
#define WS_PART 1024   // encoder partials (or gmax[64] in atomic mode)

typedef __attribute__((ext_vector_type(8))) short bf16x8;
typedef __attribute__((ext_vector_type(4))) float f32x4;

union U4 { unsigned int u[4]; bf16x8 v; };

static __device__ __forceinline__ unsigned int pack_bf16(float lo, float hi) {
    return (__float_as_uint(hi) & 0xFFFF0000u) | (__float_as_uint(lo) >> 16);
}

// ---------------- atomic-mode prologue (only if ws too small) ----------------
__global__ __launch_bounds__(64) void prep_kernel(unsigned int* __restrict__ g)
{
    g[threadIdx.x & 63] = 0u;
}

// ---------- encoder: per-point MLP 2->16->32->64 via MFMA, channel max ----------
// (identical to R6/R7 — isolate the tail change)
__global__ __launch_bounds__(256) void encoder_kernel(
    const float* __restrict__ x,
    const float* __restrict__ c1w, const float* __restrict__ c1b,
    const float* __restrict__ c2w, const float* __restrict__ c2b,
    const float* __restrict__ c3w,
    float* __restrict__ ws, int N, int use_atomic)
{
    __shared__ float sW1x[16], sW1y[16], sB1s[16];
    __shared__ float sW2[512], sB2[32];
    __shared__ float sW3[2048];
    __shared__ unsigned int sh2[4 * 272];
    __shared__ float wred[4 * 64];

    int t = threadIdx.x;
    if (t < 16) { sW1x[t] = c1w[2 * t]; sW1y[t] = c1w[2 * t + 1]; sB1s[t] = c1b[t]; }
    if (t < 32) sB2[t] = c2b[t];
    for (int i = t; i < 512; i += 256)  sW2[i] = c2w[i];
    for (int i = t; i < 2048; i += 256) sW3[i] = c3w[i];
    __syncthreads();

    const int lane = t & 63, wid = t >> 6;
    const int n16 = lane & 15, q = lane >> 4;

    bf16x8 a2[2];
#pragma unroll
    for (int tt = 0; tt < 2; ++tt)
#pragma unroll
        for (int j = 0; j < 8; ++j) {
            int k = q * 8 + j;
            float w = (k < 16) ? sW2[(tt * 16 + n16) * 16 + k] : 0.0f;
            a2[tt][j] = (short)(__float_as_uint(w) >> 16);
        }
    bf16x8 a3[4];
#pragma unroll
    for (int tt = 0; tt < 4; ++tt)
#pragma unroll
        for (int j = 0; j < 8; ++j) {
            float w = sW3[(tt * 16 + n16) * 32 + q * 8 + j];
            a3[tt][j] = (short)(__float_as_uint(w) >> 16);
        }
    float w1x[8], w1y[8], b1v[8];
#pragma unroll
    for (int j = 0; j < 8; ++j) {
        int k = q * 8 + j;
        if (k < 16) { w1x[j] = sW1x[k]; w1y[j] = sW1y[k]; b1v[j] = sB1s[k]; }
        else        { w1x[j] = 0.f;     w1y[j] = 0.f;     b1v[j] = 0.f; }
    }
    float b2a[4], b2b[4];
#pragma unroll
    for (int r = 0; r < 4; ++r) { b2a[r] = sB2[q * 4 + r]; b2b[r] = sB2[16 + q * 4 + r]; }

    float vmax[16];
#pragma unroll
    for (int i = 0; i < 16; ++i) vmax[i] = -INFINITY;

    unsigned int* hb = sh2 + wid * 272;
    const int WPG = NBLK * 4;
    const int gw = blockIdx.x * 4 + wid;
    const int niter = (N + WPG * 16 - 1) / (WPG * 16);

    int p = gw * 16 + n16; if (p >= N) p = N - 1;
    float px = x[3 + p], py = x[3 + N + p];

#pragma unroll 1
    for (int it = 0; it < niter; ++it) {
        float cpx = px, cpy = py;
        if (it + 1 < niter) {
            int pn = ((it + 1) * WPG + gw) * 16 + n16;
            if (pn >= N) pn = N - 1;
            px = x[3 + pn]; py = x[3 + N + pn];
        }

        unsigned int h1d0 = 0, h1d1 = 0, h1d2 = 0, h1d3 = 0;
        if (q < 2) {
            float h0 = fmaxf(fmaf(w1x[0], cpx, fmaf(w1y[0], cpy, b1v[0])), 0.f);
            float h1 = fmaxf(fmaf(w1x[1], cpx, fmaf(w1y[1], cpy, b1v[1])), 0.f);
            float h2 = fmaxf(fmaf(w1x[2], cpx, fmaf(w1y[2], cpy, b1v[2])), 0.f);
            float h3 = fmaxf(fmaf(w1x[3], cpx, fmaf(w1y[3], cpy, b1v[3])), 0.f);
            float h4 = fmaxf(fmaf(w1x[4], cpx, fmaf(w1y[4], cpy, b1v[4])), 0.f);
            float h5 = fmaxf(fmaf(w1x[5], cpx, fmaf(w1y[5], cpy, b1v[5])), 0.f);
            float h6 = fmaxf(fmaf(w1x[6], cpx, fmaf(w1y[6], cpy, b1v[6])), 0.f);
            float h7 = fmaxf(fmaf(w1x[7], cpx, fmaf(w1y[7], cpy, b1v[7])), 0.f);
            h1d0 = pack_bf16(h0, h1); h1d1 = pack_bf16(h2, h3);
            h1d2 = pack_bf16(h4, h5); h1d3 = pack_bf16(h6, h7);
        }
        U4 bu; bu.u[0] = h1d0; bu.u[1] = h1d1; bu.u[2] = h1d2; bu.u[3] = h1d3;

        f32x4 z4 = {0.f, 0.f, 0.f, 0.f};
        f32x4 acc2a = __builtin_amdgcn_mfma_f32_16x16x32_bf16(a2[0], bu.v, z4, 0, 0, 0);
        f32x4 acc2b = __builtin_amdgcn_mfma_f32_16x16x32_bf16(a2[1], bu.v, z4, 0, 0, 0);

        unsigned int base = (unsigned int)(n16 * 17);
        hb[base + 2 * q]     = pack_bf16(fmaxf(acc2a[0] + b2a[0], 0.f),
                                         fmaxf(acc2a[1] + b2a[1], 0.f));
        hb[base + 2 * q + 1] = pack_bf16(fmaxf(acc2a[2] + b2a[2], 0.f),
                                         fmaxf(acc2a[3] + b2a[3], 0.f));
        hb[base + 8 + 2 * q] = pack_bf16(fmaxf(acc2b[0] + b2b[0], 0.f),
                                         fmaxf(acc2b[1] + b2b[1], 0.f));
        hb[base + 9 + 2 * q] = pack_bf16(fmaxf(acc2b[2] + b2b[2], 0.f),
                                         fmaxf(acc2b[3] + b2b[3], 0.f));
        __builtin_amdgcn_s_waitcnt(0xc07f);
        U4 ru;
        ru.u[0] = hb[base + 4 * q];     ru.u[1] = hb[base + 4 * q + 1];
        ru.u[2] = hb[base + 4 * q + 2]; ru.u[3] = hb[base + 4 * q + 3];

        f32x4 o0 = __builtin_amdgcn_mfma_f32_16x16x32_bf16(a3[0], ru.v, z4, 0, 0, 0);
        f32x4 o1 = __builtin_amdgcn_mfma_f32_16x16x32_bf16(a3[1], ru.v, z4, 0, 0, 0);
        f32x4 o2 = __builtin_amdgcn_mfma_f32_16x16x32_bf16(a3[2], ru.v, z4, 0, 0, 0);
        f32x4 o3 = __builtin_amdgcn_mfma_f32_16x16x32_bf16(a3[3], ru.v, z4, 0, 0, 0);
#pragma unroll
        for (int r = 0; r < 4; ++r) {
            vmax[r]      = fmaxf(vmax[r],      o0[r]);
            vmax[4 + r]  = fmaxf(vmax[4 + r],  o1[r]);
            vmax[8 + r]  = fmaxf(vmax[8 + r],  o2[r]);
            vmax[12 + r] = fmaxf(vmax[12 + r], o3[r]);
        }
    }

#pragma unroll
    for (int i = 0; i < 16; ++i) {
        float v = vmax[i];
        v = fmaxf(v, __shfl_xor(v, 1, 64));
        v = fmaxf(v, __shfl_xor(v, 2, 64));
        v = fmaxf(v, __shfl_xor(v, 4, 64));
        v = fmaxf(v, __shfl_xor(v, 8, 64));
        vmax[i] = v;
    }
    if (n16 == 0) {
#pragma unroll
        for (int tt = 0; tt < 4; ++tt)
#pragma unroll
            for (int r = 0; r < 4; ++r)
                wred[wid * 64 + tt * 16 + q * 4 + r] = vmax[tt * 4 + r];
    }
    __syncthreads();
    if (t < 64) {
        float m = fmaxf(fmaxf(wred[t], wred[64 + t]),
                        fmaxf(wred[128 + t], wred[192 + t]));
        if (use_atomic) {
            unsigned int b = __float_as_uint(m);
            unsigned int e = (b & 0x80000000u) ? ~b : (b | 0x80000000u);
            atomicMax((unsigned int*)ws + WS_PART + t, e);
        } else {
            ws[WS_PART + blockIdx.x * 64 + t] = m;
        }
    }
}

// ---------- K1 (16 blocks): ghh = whh@hx + bhh | feat reduce | pose (b0) ----------
__global__ __launch_bounds__(256) void tail_k1(
    const float* __restrict__ x,   const float* __restrict__ hx,
    const float* __restrict__ whh, const float* __restrict__ bhh,
    const float* __restrict__ c3b,
    const float* __restrict__ o1w, const float* __restrict__ o1b,
    const float* __restrict__ o2w, const float* __restrict__ o2b,
    float* __restrict__ ws, float* __restrict__ out, int use_atomic)
{
    const int b = blockIdx.x, t = threadIdx.x;
    __shared__ float shx[128], sig8L[8], odomL[3];

    if (t < 128) shx[t] = hx[t];
    __syncthreads();

    // ghh: 32 rows/block, 8 threads/row
    {
        const int rl = t >> 3, sub = t & 7;
        const int gr = (rl >> 3) * 128 + b * 8 + (rl & 7);
        const float4* w4 = (const float4*)(whh + (size_t)gr * 128) + sub * 4;
        float s = 0.0f;
#pragma unroll
        for (int j = 0; j < 4; j++) {
            float4 w = w4[j];
            int k = sub * 16 + 4 * j;
            s = fmaf(w.x, shx[k], fmaf(w.y, shx[k + 1],
                fmaf(w.z, shx[k + 2], fmaf(w.w, shx[k + 3], s))));
        }
        s += __shfl_xor(s, 1, 64); s += __shfl_xor(s, 2, 64); s += __shfl_xor(s, 4, 64);
        if (sub == 0) ws[WS_GHH + gr] = bhh[gr] + s;
    }

    // feat reduce: 4 channels/block
    if (!use_atomic) {
        int w = t >> 6, lane = t & 63;
        int c = b * 4 + w;
        float m = -INFINITY;
        const float* part = ws + WS_PART;
#pragma unroll 4
        for (int j = 0; j < NBLK / 64; j++)
            m = fmaxf(m, part[(lane * (NBLK / 64) + j) * 64 + c]);
#pragma unroll
        for (int off = 32; off > 0; off >>= 1)
            m = fmaxf(m, __shfl_xor(m, off, 64));
        if (lane == 0) ws[WS_FEAT + c] = fmaxf(m + c3b[c], 0.0f);
    } else if (b == 0 && t >= 64 && t < 128) {
        int c = t - 64;
        unsigned int u = ((unsigned int*)ws)[WS_PART + c];
        unsigned int bb = (u & 0x80000000u) ? (u ^ 0x80000000u) : ~u;
        ws[WS_FEAT + c] = fmaxf(__uint_as_float(bb) + c3b[c], 0.0f);
    }

    // pose chain (block 0)
    if (b == 0) {
        if (t < 3) odomL[t] = x[t];
        __syncthreads();
        if (t < 8) {
            float s = o1b[t];
            for (int k = 0; k < 3; k++) s = fmaf(o1w[t * 3 + k], odomL[k], s);
            sig8L[t] = 1.0f / (1.0f + expf(-s));
        }
        __syncthreads();
        if (t < 8) {
            float s = o2b[t];
            for (int k = 0; k < 8; k++) s = fmaf(o2w[t * 8 + k], sig8L[k], s);
            float pv = fmaxf(s, 0.0f);
            ws[WS_POSE + t] = pv;
            out[263 + t] = pv;
        }
    }
}

// ---------- K2a (16 blocks): obs rows = fcw @ feat + fcb ----------
__global__ __launch_bounds__(256) void tail_k2a(
    const float* __restrict__ fcw, const float* __restrict__ fcb,
    float* __restrict__ ws)
{
    const int b = blockIdx.x, t = threadIdx.x;
    __shared__ float featL[64];
    if (t < 64) featL[t] = ws[WS_FEAT + t];
    __syncthreads();
    int row = b * 4 + (t >> 6), lane = t & 63;
    float s = fcw[(size_t)row * 64 + lane] * featL[lane];
#pragma unroll
    for (int off = 32; off > 0; off >>= 1) s += __shfl_xor(s, off, 64);
    if (lane == 0) ws[WS_OBS + row] = s + fcb[row];
}

// ---------- K2b (16 blocks): z rows = relu(pw @ [obs;pose] + pb) ----------
__global__ __launch_bounds__(256) void tail_k2b(
    const float* __restrict__ pw, const float* __restrict__ pb,
    float* __restrict__ ws)
{
    const int b = blockIdx.x, t = threadIdx.x;
    __shared__ float inL[72];
    if (t < 64) inL[t] = ws[WS_OBS + t];
    else if (t < 72) inL[t] = ws[WS_POSE + t - 64];
    __syncthreads();
    int rowl = t >> 5, l32 = t & 31;
    int row = b * 8 + rowl;
    const float* wr = pw + (size_t)row * 72;
    float s = wr[l32] * inL[l32] + wr[l32 + 32] * inL[l32 + 32];
    if (l32 < 8) s = fmaf(wr[l32 + 64], inL[l32 + 64], s);
    s += __shfl_xor(s, 1, 64); s += __shfl_xor(s, 2, 64);
    s += __shfl_xor(s, 4, 64); s += __shfl_xor(s, 8, 64); s += __shfl_xor(s, 16, 64);
    if (l32 == 0) ws[WS_Z + row] = fmaxf(s + pb[row], 0.0f);
}

// ---------- K3 (16 blocks): gates = wih@z + bih + ghh; LSTM cell update ----------
__global__ __launch_bounds__(256) void tail_k3(
    const float* __restrict__ wih, const float* __restrict__ bih,
    const float* __restrict__ cx,
    float* __restrict__ ws, float* __restrict__ out)
{
    const int b = blockIdx.x, t = threadIdx.x;
    __shared__ float zL[128], lg[32];
    if (t < 128) zL[t] = ws[WS_Z + t];
    __syncthreads();

    const int rl = t >> 3, sub = t & 7;
    const int gr = (rl >> 3) * 128 + b * 8 + (rl & 7);
    const float4* w4 = (const float4*)(wih + (size_t)gr * 128) + sub * 4;
    float s = 0.0f;
#pragma unroll
    for (int j = 0; j < 4; j++) {
        float4 w = w4[j];
        int k = sub * 16 + 4 * j;
        s = fmaf(w.x, zL[k], fmaf(w.y, zL[k + 1],
            fmaf(w.z, zL[k + 2], fmaf(w.w, zL[k + 3], s))));
    }
    s += __shfl_xor(s, 1, 64); s += __shfl_xor(s, 2, 64); s += __shfl_xor(s, 4, 64);
    if (sub == 0) lg[rl] = ws[WS_GHH + gr] + bih[gr] + s;
    __syncthreads();

    if (t < 8) {
        int c = b * 8 + t;
        float gI = lg[t], gF = lg[8 + t], gG = lg[16 + t], gO = lg[24 + t];
        float ig = 1.0f / (1.0f + expf(-gI));
        float fg = 1.0f / (1.0f + expf(-gF));
        float gg = tanhf(gG);
        float og = 1.0f / (1.0f + expf(-gO));
        float cn = fg * cx[c] + ig * gg;
        float hn = og * tanhf(cn);
        out[7 + c] = hn;
        out[135 + c] = cn;
        ws[WS_HNEW + c] = hn;
    }
}

// ---------- K4 (16 blocks): zp1 rows = relu(q1w @ hnew + q1b) ----------
__global__ __launch_bounds__(256) void tail_k4(
    const float* __restrict__ q1w, const float* __restrict__ q1b,
    float* __restrict__ ws)
{
    const int b = blockIdx.x, t = threadIdx.x;
    __shared__ float hnL[128];
    if (t < 128) hnL[t] = ws[WS_HNEW + t];
    __syncthreads();
    int row = b * 4 + (t >> 6), lane = t & 63;
    const float* wr = q1w + (size_t)row * 128;
    float s = fmaf(wr[2 * lane], hnL[2 * lane], wr[2 * lane + 1] * hnL[2 * lane + 1]);
#pragma unroll
    for (int off = 32; off > 0; off >>= 1) s += __shfl_xor(s, off, 64);
    if (lane == 0) ws[WS_ZP1 + row] = fmaxf(s + q1b[row], 0.0f);
}

// ---------- K5 (1 block): zp2 + heads + softmax ----------
__global__ __launch_bounds__(256) void tail_k5(
    const float* __restrict__ q2w, const float* __restrict__ q2b,
    const float* __restrict__ aw1, const float* __restrict__ ab1,
    const float* __restrict__ aw2, const float* __restrict__ ab2,
    const float* __restrict__ ciw1, const float* __restrict__ cib1,
    const float* __restrict__ ciw2, const float* __restrict__ cib2,
    const float* __restrict__ cew1, const float* __restrict__ ceb1,
    const float* __restrict__ cew2, const float* __restrict__ ceb2,
    const float* __restrict__ ws, float* __restrict__ out)
{
    const int t = threadIdx.x;
    __shared__ float zp1L[64], zp2L[64], a1s[16], cih[16], ceh[16], logits[5];
    if (t < 64) zp1L[t] = ws[WS_ZP1 + t];
    __syncthreads();
    if (t < 64) {
        float s = q2b[t];
        const float4* q4 = (const float4*)(q2w + (size_t)t * 64);
        for (int qq = 0; qq < 16; qq++) {
            float4 w = q4[qq];
            s = fmaf(w.x, zp1L[4 * qq], fmaf(w.y, zp1L[4 * qq + 1],
                fmaf(w.z, zp1L[4 * qq + 2], fmaf(w.w, zp1L[4 * qq + 3], s))));
        }
        zp2L[t] = fmaxf(s, 0.0f);
    }
    __syncthreads();
    if (t < 16) {
        float s = ab1[t];
        for (int k = 0; k < 64; k++) s = fmaf(aw1[t * 64 + k], zp2L[k], s);
        a1s[t] = fmaxf(s, 0.0f);
    } else if (t < 32) {
        int r = t - 16;
        float s = cib1[r];
        for (int k = 0; k < 64; k++) s = fmaf(ciw1[r * 64 + k], zp2L[k], s);
        cih[r] = fmaxf(s, 0.0f);
    } else if (t < 48) {
        int r = t - 32;
        float s = ceb1[r];
        for (int k = 0; k < 64; k++) s = fmaf(cew1[r * 64 + k], zp2L[k], s);
        ceh[r] = fmaxf(s, 0.0f);
    }
    __syncthreads();
    if (t < 5) {
        float s = ab2[t];
        for (int k = 0; k < 16; k++) s = fmaf(aw2[t * 16 + k], a1s[k], s);
        logits[t] = s;
    } else if (t == 5) {
        float s = cib2[0];
        for (int k = 0; k < 16; k++) s = fmaf(ciw2[k], cih[k], s);
        out[5] = s;
    } else if (t == 6) {
        float s = ceb2[0];
        for (int k = 0; k < 16; k++) s = fmaf(cew2[k], ceh[k], s);
        out[6] = s;
    }
    __syncthreads();
    if (t == 0) {
        float m = logits[0];
        for (int i = 1; i < 5; i++) m = fmaxf(m, logits[i]);
        float e[5], s = 0.0f;
        for (int i = 0; i < 5; i++) { e[i] = expf(logits[i] - m); s += e[i]; }
        for (int i = 0; i < 5; i++) out[i] = e[i] / s;
    }
}

extern "C" void kernel_launch(void* const* d_in, const int* in_sizes, int n_in,
                              void* d_out, int out_size, void* d_ws, size_t ws_size,
                              hipStream_t stream)
{
    const float* x    = (const float*)d_in[0];
    const float* hx   = (const float*)d_in[1];
    const float* cx   = (const float*)d_in[2];
    const float* c1w  = (const float*)d_in[3];
    const float* c1b  = (const float*)d_in[4];
    const float* c2w  = (const float*)d_in[5];
    const float* c2b  = (const float*)d_in[6];
    const float* c3w  = (const float*)d_in[7];
    const float* c3b  = (const float*)d_in[8];
    const float* fcw  = (const float*)d_in[9];
    const float* fcb  = (const float*)d_in[10];
    const float* o1w  = (const float*)d_in[11];
    const float* o1b  = (const float*)d_in[12];
    const float* o2w  = (const float*)d_in[13];
    const float* o2b  = (const float*)d_in[14];
    const float* pw   = (const float*)d_in[15];
    const float* pb   = (const float*)d_in[16];
    const float* wih  = (const float*)d_in[17];
    const float* whh  = (const float*)d_in[18];
    const float* bih  = (const float*)d_in[19];
    const float* bhh  = (const float*)d_in[20];
    const float* q1w  = (const float*)d_in[21];
    const float* q1b  = (const float*)d_in[22];
    const float* q2w  = (const float*)d_in[23];
    const float* q2b  = (const float*)d_in[24];
    const float* aw1  = (const float*)d_in[25];
    const float* ab1  = (const float*)d_in[26];
    const float* aw2  = (const float*)d_in[27];
    const float* ab2  = (const float*)d_in[28];
    const float* ciw1 = (const float*)d_in[29];
    const float* cib1 = (const float*)d_in[30];
    const float* ciw2 = (const float*)d_in[31];
    const float* cib2 = (const float*)d_in[32];
    const float* cew1 = (const float*)d_in[33];
    const float* ceb1 = (const float*)d_in[34];
    const float* cew2 = (const float*)d_in[35];
    const float* ceb2 = (const float*)d_in[36];

    int N = (in_sizes[0] - 3) / 2;
    size_t need = (size_t)(1024 + NBLK * 64) * 4;
    int use_atomic = (ws_size < need) ? 1 : 0;
    float* ws = (float*)d_ws;
    float* out = (float*)d_out;

    if (use_atomic)
        prep_kernel<<<1, 64, 0, stream>>>((unsigned int*)d_ws + WS_PART);
    encoder_kernel<<<NBLK, 256, 0, stream>>>(x, c1w, c1b, c2w, c2b, c3w,
                                             ws, N, use_atomic);
    tail_k1<<<16, 256, 0, stream>>>(x, hx, whh, bhh, c3b, o1w, o1b, o2w, o2b,
                                    ws, out, use_atomic);
    tail_k2a<<<16, 256, 0, stream>>>(fcw, fcb, ws);
    tail_k2b<<<16, 256, 0, stream>>>(pw, pb, ws);
    tail_k3<<<16, 256, 0, stream>>>(wih, bih, cx, ws, out);
    tail_k4<<<16, 256, 0, stream>>>(q1w, q1b, ws);
    tail_k5<<<1, 256, 0, stream>>>(q2w, q2b, aw1, ab1, aw2, ab2, ciw1, cib1,
                                   ciw2, cib2, cew1, ceb1, cew2, ceb2, ws, out);
}

// Round 9
// 159.908 us; speedup vs baseline: 1.4897x; 1.0056x over previous
//
#include <hip/hip_runtime.h>

#define NBLK 1024   // encoder grid; partials live at ws[1024 .. 1024+NBLK*64)

// ws float layout:
#define WS_Z    0      // [0..127]   z                    (cross-block: AGENT)
#define WS_GHH  128    // [128..639] whh@hx + bhh         (same-block only)
#define WS_HNEW 640    // [640..767] h_new                (cross-block: AGENT)
#define WS_ZP1  768    // [768..831] zp1                  (cross-block: AGENT)
#define WS_FEAT 840    // [840..903] feat post bias+relu  (cross-block: AGENT)
#define WS_BAR  992    // [992..999] spin-barrier counters (uint, zeroed by encoder)
#define WS_PART 1024   // encoder partials (or gmax[64] in atomic mode)

#define NTB 16         // tail blocks

typedef __attribute__((ext_vector_type(8))) short bf16x8;
typedef __attribute__((ext_vector_type(4))) float f32x4;

union U4 { unsigned int u[4]; bf16x8 v; };

static __device__ __forceinline__ unsigned int pack_bf16(float lo, float hi) {
    return (__float_as_uint(hi) & 0xFFFF0000u) | (__float_as_uint(lo) >> 16);
}

static __device__ __forceinline__ void ag_store(float* p, float v) {
    __hip_atomic_store(p, v, __ATOMIC_RELEASE, __HIP_MEMORY_SCOPE_AGENT);
}
static __device__ __forceinline__ float ag_load(const float* p) {
    return __hip_atomic_load(p, __ATOMIC_ACQUIRE, __HIP_MEMORY_SCOPE_AGENT);
}

// 16-block spin barrier (device-scope; safe: 16 blocks always co-resident)
static __device__ __forceinline__ void bar_sync(unsigned int* bar, int idx) {
    __syncthreads();
    if (threadIdx.x == 0) {
        __hip_atomic_fetch_add(&bar[idx], 1u, __ATOMIC_ACQ_REL, __HIP_MEMORY_SCOPE_AGENT);
        while (__hip_atomic_load(&bar[idx], __ATOMIC_ACQUIRE,
                                 __HIP_MEMORY_SCOPE_AGENT) < NTB) {}
    }
    __syncthreads();
}

// ---------------- atomic-mode prologue (only if ws too small) ----------------
__global__ __launch_bounds__(64) void prep_kernel(unsigned int* __restrict__ g)
{
    g[threadIdx.x & 63] = 0u;
}

// ---------- encoder: per-point MLP 2->16->32->64 via MFMA, channel max ----------
// (identical to R6-R8 except block 0 zeroes the tail's barrier counters)
__global__ __launch_bounds__(256) void encoder_kernel(
    const float* __restrict__ x,
    const float* __restrict__ c1w, const float* __restrict__ c1b,
    const float* __restrict__ c2w, const float* __restrict__ c2b,
    const float* __restrict__ c3w,
    float* __restrict__ ws, int N, int use_atomic)
{
    __shared__ float sW1x[16], sW1y[16], sB1s[16];
    __shared__ float sW2[512], sB2[32];
    __shared__ float sW3[2048];
    __shared__ unsigned int sh2[4 * 272];
    __shared__ float wred[4 * 64];

    int t = threadIdx.x;
    if (blockIdx.x == 0 && t < 8) ((unsigned int*)ws)[WS_BAR + t] = 0u;
    if (t < 16) { sW1x[t] = c1w[2 * t]; sW1y[t] = c1w[2 * t + 1]; sB1s[t] = c1b[t]; }
    if (t < 32) sB2[t] = c2b[t];
    for (int i = t; i < 512; i += 256)  sW2[i] = c2w[i];
    for (int i = t; i < 2048; i += 256) sW3[i] = c3w[i];
    __syncthreads();

    const int lane = t & 63, wid = t >> 6;
    const int n16 = lane & 15, q = lane >> 4;

    bf16x8 a2[2];
#pragma unroll
    for (int tt = 0; tt < 2; ++tt)
#pragma unroll
        for (int j = 0; j < 8; ++j) {
            int k = q * 8 + j;
            float w = (k < 16) ? sW2[(tt * 16 + n16) * 16 + k] : 0.0f;
            a2[tt][j] = (short)(__float_as_uint(w) >> 16);
        }
    bf16x8 a3[4];
#pragma unroll
    for (int tt = 0; tt < 4; ++tt)
#pragma unroll
        for (int j = 0; j < 8; ++j) {
            float w = sW3[(tt * 16 + n16) * 32 + q * 8 + j];
            a3[tt][j] = (short)(__float_as_uint(w) >> 16);
        }
    float w1x[8], w1y[8], b1v[8];
#pragma unroll
    for (int j = 0; j < 8; ++j) {
        int k = q * 8 + j;
        if (k < 16) { w1x[j] = sW1x[k]; w1y[j] = sW1y[k]; b1v[j] = sB1s[k]; }
        else        { w1x[j] = 0.f;     w1y[j] = 0.f;     b1v[j] = 0.f; }
    }
    float b2a[4], b2b[4];
#pragma unroll
    for (int r = 0; r < 4; ++r) { b2a[r] = sB2[q * 4 + r]; b2b[r] = sB2[16 + q * 4 + r]; }

    float vmax[16];
#pragma unroll
    for (int i = 0; i < 16; ++i) vmax[i] = -INFINITY;

    unsigned int* hb = sh2 + wid * 272;
    const int WPG = NBLK * 4;
    const int gw = blockIdx.x * 4 + wid;
    const int niter = (N + WPG * 16 - 1) / (WPG * 16);

    int p = gw * 16 + n16; if (p >= N) p = N - 1;
    float px = x[3 + p], py = x[3 + N + p];

#pragma unroll 1
    for (int it = 0; it < niter; ++it) {
        float cpx = px, cpy = py;
        if (it + 1 < niter) {
            int pn = ((it + 1) * WPG + gw) * 16 + n16;
            if (pn >= N) pn = N - 1;
            px = x[3 + pn]; py = x[3 + N + pn];
        }

        unsigned int h1d0 = 0, h1d1 = 0, h1d2 = 0, h1d3 = 0;
        if (q < 2) {
            float h0 = fmaxf(fmaf(w1x[0], cpx, fmaf(w1y[0], cpy, b1v[0])), 0.f);
            float h1 = fmaxf(fmaf(w1x[1], cpx, fmaf(w1y[1], cpy, b1v[1])), 0.f);
            float h2 = fmaxf(fmaf(w1x[2], cpx, fmaf(w1y[2], cpy, b1v[2])), 0.f);
            float h3 = fmaxf(fmaf(w1x[3], cpx, fmaf(w1y[3], cpy, b1v[3])), 0.f);
            float h4 = fmaxf(fmaf(w1x[4], cpx, fmaf(w1y[4], cpy, b1v[4])), 0.f);
            float h5 = fmaxf(fmaf(w1x[5], cpx, fmaf(w1y[5], cpy, b1v[5])), 0.f);
            float h6 = fmaxf(fmaf(w1x[6], cpx, fmaf(w1y[6], cpy, b1v[6])), 0.f);
            float h7 = fmaxf(fmaf(w1x[7], cpx, fmaf(w1y[7], cpy, b1v[7])), 0.f);
            h1d0 = pack_bf16(h0, h1); h1d1 = pack_bf16(h2, h3);
            h1d2 = pack_bf16(h4, h5); h1d3 = pack_bf16(h6, h7);
        }
        U4 bu; bu.u[0] = h1d0; bu.u[1] = h1d1; bu.u[2] = h1d2; bu.u[3] = h1d3;

        f32x4 z4 = {0.f, 0.f, 0.f, 0.f};
        f32x4 acc2a = __builtin_amdgcn_mfma_f32_16x16x32_bf16(a2[0], bu.v, z4, 0, 0, 0);
        f32x4 acc2b = __builtin_amdgcn_mfma_f32_16x16x32_bf16(a2[1], bu.v, z4, 0, 0, 0);

        unsigned int base = (unsigned int)(n16 * 17);
        hb[base + 2 * q]     = pack_bf16(fmaxf(acc2a[0] + b2a[0], 0.f),
                                         fmaxf(acc2a[1] + b2a[1], 0.f));
        hb[base + 2 * q + 1] = pack_bf16(fmaxf(acc2a[2] + b2a[2], 0.f),
                                         fmaxf(acc2a[3] + b2a[3], 0.f));
        hb[base + 8 + 2 * q] = pack_bf16(fmaxf(acc2b[0] + b2b[0], 0.f),
                                         fmaxf(acc2b[1] + b2b[1], 0.f));
        hb[base + 9 + 2 * q] = pack_bf16(fmaxf(acc2b[2] + b2b[2], 0.f),
                                         fmaxf(acc2b[3] + b2b[3], 0.f));
        __builtin_amdgcn_s_waitcnt(0xc07f);
        U4 ru;
        ru.u[0] = hb[base + 4 * q];     ru.u[1] = hb[base + 4 * q + 1];
        ru.u[2] = hb[base + 4 * q + 2]; ru.u[3] = hb[base + 4 * q + 3];

        f32x4 o0 = __builtin_amdgcn_mfma_f32_16x16x32_bf16(a3[0], ru.v, z4, 0, 0, 0);
        f32x4 o1 = __builtin_amdgcn_mfma_f32_16x16x32_bf16(a3[1], ru.v, z4, 0, 0, 0);
        f32x4 o2 = __builtin_amdgcn_mfma_f32_16x16x32_bf16(a3[2], ru.v, z4, 0, 0, 0);
        f32x4 o3 = __builtin_amdgcn_mfma_f32_16x16x32_bf16(a3[3], ru.v, z4, 0, 0, 0);
#pragma unroll
        for (int r = 0; r < 4; ++r) {
            vmax[r]      = fmaxf(vmax[r],      o0[r]);
            vmax[4 + r]  = fmaxf(vmax[4 + r],  o1[r]);
            vmax[8 + r]  = fmaxf(vmax[8 + r],  o2[r]);
            vmax[12 + r] = fmaxf(vmax[12 + r], o3[r]);
        }
    }

#pragma unroll
    for (int i = 0; i < 16; ++i) {
        float v = vmax[i];
        v = fmaxf(v, __shfl_xor(v, 1, 64));
        v = fmaxf(v, __shfl_xor(v, 2, 64));
        v = fmaxf(v, __shfl_xor(v, 4, 64));
        v = fmaxf(v, __shfl_xor(v, 8, 64));
        vmax[i] = v;
    }
    if (n16 == 0) {
#pragma unroll
        for (int tt = 0; tt < 4; ++tt)
#pragma unroll
            for (int r = 0; r < 4; ++r)
                wred[wid * 64 + tt * 16 + q * 4 + r] = vmax[tt * 4 + r];
    }
    __syncthreads();
    if (t < 64) {
        float m = fmaxf(fmaxf(wred[t], wred[64 + t]),
                        fmaxf(wred[128 + t], wred[192 + t]));
        if (use_atomic) {
            unsigned int b = __float_as_uint(m);
            unsigned int e = (b & 0x80000000u) ? ~b : (b | 0x80000000u);
            atomicMax((unsigned int*)ws + WS_PART + t, e);
        } else {
            ws[WS_PART + blockIdx.x * 64 + t] = m;
        }
    }
}

// ---------- fused tail: 16 blocks, 4 device-scope spin barriers ----------
__global__ __launch_bounds__(256) void tail_fused(
    const float* __restrict__ x,   const float* __restrict__ hx,
    const float* __restrict__ cx,  const float* __restrict__ c3b,
    const float* __restrict__ fcw, const float* __restrict__ fcb,
    const float* __restrict__ o1w, const float* __restrict__ o1b,
    const float* __restrict__ o2w, const float* __restrict__ o2b,
    const float* __restrict__ pw,  const float* __restrict__ pb,
    const float* __restrict__ wih, const float* __restrict__ whh,
    const float* __restrict__ bih, const float* __restrict__ bhh,
    const float* __restrict__ q1w, const float* __restrict__ q1b,
    const float* __restrict__ q2w, const float* __restrict__ q2b,
    const float* __restrict__ aw1, const float* __restrict__ ab1,
    const float* __restrict__ aw2, const float* __restrict__ ab2,
    const float* __restrict__ ciw1, const float* __restrict__ cib1,
    const float* __restrict__ ciw2, const float* __restrict__ cib2,
    const float* __restrict__ cew1, const float* __restrict__ ceb1,
    const float* __restrict__ cew2, const float* __restrict__ ceb2,
    float* __restrict__ ws, float* __restrict__ out, int use_atomic)
{
    const int b = blockIdx.x, t = threadIdx.x;
    unsigned int* bar = (unsigned int*)ws + WS_BAR;
    __shared__ float shx[128], inL[72], zL[128], lg[32], hnL[128];
    __shared__ float featL[64], obsL[64], zp1L[64], zp2L[64];
    __shared__ float sig8L[8], odomL[3], poseL[8];
    __shared__ float a1s[16], cih[16], ceh[16], logits[5];

    // ---- P0: ghh rows (all) + feat reduce (all) + pose (b0) ----
    if (t < 128) shx[t] = hx[t];
    __syncthreads();
    {
        const int rl = t >> 3, sub = t & 7;
        const int gr = (rl >> 3) * 128 + b * 8 + (rl & 7);
        const float4* w4 = (const float4*)(whh + (size_t)gr * 128) + sub * 4;
        float s = 0.0f;
#pragma unroll
        for (int j = 0; j < 4; j++) {
            float4 w = w4[j];
            int k = sub * 16 + 4 * j;
            s = fmaf(w.x, shx[k], fmaf(w.y, shx[k + 1],
                fmaf(w.z, shx[k + 2], fmaf(w.w, shx[k + 3], s))));
        }
        s += __shfl_xor(s, 1, 64); s += __shfl_xor(s, 2, 64); s += __shfl_xor(s, 4, 64);
        if (sub == 0) ws[WS_GHH + gr] = bhh[gr] + s;   // same-block consumer (P2)
    }
    if (!use_atomic) {
        int w = t >> 6, lane = t & 63;
        int c = b * 4 + w;
        float m = -INFINITY;
        const float* part = ws + WS_PART;
#pragma unroll 4
        for (int j = 0; j < NBLK / 64; j++)
            m = fmaxf(m, part[(lane * (NBLK / 64) + j) * 64 + c]);
#pragma unroll
        for (int off = 32; off > 0; off >>= 1)
            m = fmaxf(m, __shfl_xor(m, off, 64));
        if (lane == 0) ag_store(&ws[WS_FEAT + c], fmaxf(m + c3b[c], 0.0f));
    } else if (b == 0 && t >= 128 && t < 192) {
        int c = t - 128;
        unsigned int u = ((unsigned int*)ws)[WS_PART + c];
        unsigned int bb = (u & 0x80000000u) ? (u ^ 0x80000000u) : ~u;
        ag_store(&ws[WS_FEAT + c], fmaxf(__uint_as_float(bb) + c3b[c], 0.0f));
    }
    if (b == 0) {
        if (t < 3) odomL[t] = x[t];
        __syncthreads();
        if (t < 8) {
            float s = o1b[t];
            for (int k = 0; k < 3; k++) s = fmaf(o1w[t * 3 + k], odomL[k], s);
            sig8L[t] = 1.0f / (1.0f + expf(-s));
        }
        __syncthreads();
        if (t < 8) {
            float s = o2b[t];
            for (int k = 0; k < 8; k++) s = fmaf(o2w[t * 8 + k], sig8L[k], s);
            float pv = fmaxf(s, 0.0f);
            poseL[t] = pv;
            out[263 + t] = pv;
        }
    }
    bar_sync(bar, 0);

    // ---- P1 (b0 only): obs = fcw@feat+fcb ; z = relu(pw@[obs;pose]+pb) ----
    if (b == 0) {
        if (t < 64) featL[t] = ag_load(&ws[WS_FEAT + t]);
        __syncthreads();
        {   // obs: 64 rows x 4 sub-threads (16 elems each)
            int row = t >> 2, sub = t & 3;
            const float4* f4 = (const float4*)(fcw + (size_t)row * 64) + sub * 4;
            float s = 0.0f;
#pragma unroll
            for (int j = 0; j < 4; j++) {
                float4 w = f4[j];
                int k = sub * 16 + 4 * j;
                s = fmaf(w.x, featL[k], fmaf(w.y, featL[k + 1],
                    fmaf(w.z, featL[k + 2], fmaf(w.w, featL[k + 3], s))));
            }
            s += __shfl_xor(s, 1, 64); s += __shfl_xor(s, 2, 64);
            if (sub == 0) obsL[row] = s + fcb[row];
        }
        __syncthreads();
        if (t < 64) inL[t] = obsL[t];
        else if (t < 72) inL[t] = poseL[t - 64];
        __syncthreads();
        {   // z: 128 rows x 2 sub-threads (36 elems each)
            int row = t >> 1, sub = t & 1;
            const float4* p4 = (const float4*)(pw + (size_t)row * 72) + sub * 9;
            float s = 0.0f;
#pragma unroll
            for (int j = 0; j < 9; j++) {
                float4 w = p4[j];
                int k = sub * 36 + 4 * j;
                s = fmaf(w.x, inL[k], fmaf(w.y, inL[k + 1],
                    fmaf(w.z, inL[k + 2], fmaf(w.w, inL[k + 3], s))));
            }
            s += __shfl_xor(s, 1, 64);
            if (sub == 0) ag_store(&ws[WS_Z + row], fmaxf(s + pb[row], 0.0f));
        }
    }
    bar_sync(bar, 1);

    // ---- P2 (all): gates = wih@z + bih + ghh; LSTM cell update (8 cells/block) ----
    if (t < 128) zL[t] = ag_load(&ws[WS_Z + t]);
    __syncthreads();
    {
        const int rl = t >> 3, sub = t & 7;
        const int gr = (rl >> 3) * 128 + b * 8 + (rl & 7);
        const float4* w4 = (const float4*)(wih + (size_t)gr * 128) + sub * 4;
        float s = 0.0f;
#pragma unroll
        for (int j = 0; j < 4; j++) {
            float4 w = w4[j];
            int k = sub * 16 + 4 * j;
            s = fmaf(w.x, zL[k], fmaf(w.y, zL[k + 1],
                fmaf(w.z, zL[k + 2], fmaf(w.w, zL[k + 3], s))));
        }
        s += __shfl_xor(s, 1, 64); s += __shfl_xor(s, 2, 64); s += __shfl_xor(s, 4, 64);
        if (sub == 0) lg[rl] = ws[WS_GHH + gr] + bih[gr] + s;
    }
    __syncthreads();
    if (t < 8) {
        int c = b * 8 + t;
        float gI = lg[t], gF = lg[8 + t], gG = lg[16 + t], gO = lg[24 + t];
        float ig = 1.0f / (1.0f + expf(-gI));
        float fg = 1.0f / (1.0f + expf(-gF));
        float gg = tanhf(gG);
        float og = 1.0f / (1.0f + expf(-gO));
        float cn = fg * cx[c] + ig * gg;
        float hn = og * tanhf(cn);
        out[7 + c] = hn;
        out[135 + c] = cn;
        ag_store(&ws[WS_HNEW + c], hn);
    }
    bar_sync(bar, 2);

    // ---- P3 (all): zp1 rows, 4/block ----
    if (t < 128) hnL[t] = ag_load(&ws[WS_HNEW + t]);
    __syncthreads();
    {
        int row = b * 4 + (t >> 6), lane = t & 63;
        const float* wr = q1w + (size_t)row * 128;
        float s = fmaf(wr[2 * lane], hnL[2 * lane], wr[2 * lane + 1] * hnL[2 * lane + 1]);
#pragma unroll
        for (int off = 32; off > 0; off >>= 1) s += __shfl_xor(s, off, 64);
        if (lane == 0) ag_store(&ws[WS_ZP1 + row], fmaxf(s + q1b[row], 0.0f));
    }
    bar_sync(bar, 3);

    // ---- P4 (b0 only): zp2 + heads + softmax ----
    if (b == 0) {
        if (t < 64) zp1L[t] = ag_load(&ws[WS_ZP1 + t]);
        __syncthreads();
        {   // zp2: 64 rows x 4 sub-threads
            int row = t >> 2, sub = t & 3;
            const float4* q4 = (const float4*)(q2w + (size_t)row * 64) + sub * 4;
            float s = 0.0f;
#pragma unroll
            for (int j = 0; j < 4; j++) {
                float4 w = q4[j];
                int k = sub * 16 + 4 * j;
                s = fmaf(w.x, zp1L[k], fmaf(w.y, zp1L[k + 1],
                    fmaf(w.z, zp1L[k + 2], fmaf(w.w, zp1L[k + 3], s))));
            }
            s += __shfl_xor(s, 1, 64); s += __shfl_xor(s, 2, 64);
            if (sub == 0) zp2L[row] = fmaxf(s + q2b[row], 0.0f);
        }
        __syncthreads();
        if (t < 16) {
            float s = ab1[t];
            for (int k = 0; k < 64; k++) s = fmaf(aw1[t * 64 + k], zp2L[k], s);
            a1s[t] = fmaxf(s, 0.0f);
        } else if (t < 32) {
            int r = t - 16;
            float s = cib1[r];
            for (int k = 0; k < 64; k++) s = fmaf(ciw1[r * 64 + k], zp2L[k], s);
            cih[r] = fmaxf(s, 0.0f);
        } else if (t < 48) {
            int r = t - 32;
            float s = ceb1[r];
            for (int k = 0; k < 64; k++) s = fmaf(cew1[r * 64 + k], zp2L[k], s);
            ceh[r] = fmaxf(s, 0.0f);
        }
        __syncthreads();
        if (t < 5) {
            float s = ab2[t];
            for (int k = 0; k < 16; k++) s = fmaf(aw2[t * 16 + k], a1s[k], s);
            logits[t] = s;
        } else if (t == 5) {
            float s = cib2[0];
            for (int k = 0; k < 16; k++) s = fmaf(ciw2[k], cih[k], s);
            out[5] = s;
        } else if (t == 6) {
            float s = ceb2[0];
            for (int k = 0; k < 16; k++) s = fmaf(cew2[k], ceh[k], s);
            out[6] = s;
        }
        __syncthreads();
        if (t == 0) {
            float m = logits[0];
            for (int i = 1; i < 5; i++) m = fmaxf(m, logits[i]);
            float e[5], s = 0.0f;
            for (int i = 0; i < 5; i++) { e[i] = expf(logits[i] - m); s += e[i]; }
            for (int i = 0; i < 5; i++) out[i] = e[i] / s;
        }
    }
}

extern "C" void kernel_launch(void* const* d_in, const int* in_sizes, int n_in,
                              void* d_out, int out_size, void* d_ws, size_t ws_size,
                              hipStream_t stream)
{
    const float* x    = (const float*)d_in[0];
    const float* hx   = (const float*)d_in[1];
    const float* cx   = (const float*)d_in[2];
    const float* c1w  = (const float*)d_in[3];
    const float* c1b  = (const float*)d_in[4];
    const float* c2w  = (const float*)d_in[5];
    const float* c2b  = (const float*)d_in[6];
    const float* c3w  = (const float*)d_in[7];
    const float* c3b  = (const float*)d_in[8];
    const float* fcw  = (const float*)d_in[9];
    const float* fcb  = (const float*)d_in[10];
    const float* o1w  = (const float*)d_in[11];
    const float* o1b  = (const float*)d_in[12];
    const float* o2w  = (const float*)d_in[13];
    const float* o2b  = (const float*)d_in[14];
    const float* pw   = (const float*)d_in[15];
    const float* pb   = (const float*)d_in[16];
    const float* wih  = (const float*)d_in[17];
    const float* whh  = (const float*)d_in[18];
    const float* bih  = (const float*)d_in[19];
    const float* bhh  = (const float*)d_in[20];
    const float* q1w  = (const float*)d_in[21];
    const float* q1b  = (const float*)d_in[22];
    const float* q2w  = (const float*)d_in[23];
    const float* q2b  = (const float*)d_in[24];
    const float* aw1  = (const float*)d_in[25];
    const float* ab1  = (const float*)d_in[26];
    const float* aw2  = (const float*)d_in[27];
    const float* ab2  = (const float*)d_in[28];
    const float* ciw1 = (const float*)d_in[29];
    const float* cib1 = (const float*)d_in[30];
    const float* ciw2 = (const float*)d_in[31];
    const float* cib2 = (const float*)d_in[32];
    const float* cew1 = (const float*)d_in[33];
    const float* ceb1 = (const float*)d_in[34];
    const float* cew2 = (const float*)d_in[35];
    const float* ceb2 = (const float*)d_in[36];

    int N = (in_sizes[0] - 3) / 2;
    size_t need = (size_t)(1024 + NBLK * 64) * 4;
    int use_atomic = (ws_size < need) ? 1 : 0;
    float* ws = (float*)d_ws;
    float* out = (float*)d_out;

    if (use_atomic)
        prep_kernel<<<1, 64, 0, stream>>>((unsigned int*)d_ws + WS_PART);
    encoder_kernel<<<NBLK, 256, 0, stream>>>(x, c1w, c1b, c2w, c2b, c3w,
                                             ws, N, use_atomic);
    tail_fused<<<NTB, 256, 0, stream>>>(x, hx, cx, c3b, fcw, fcb, o1w, o1b,
                                        o2w, o2b, pw, pb, wih, whh, bih, bhh,
                                        q1w, q1b, q2w, q2b, aw1, ab1, aw2, ab2,
                                        ciw1, cib1, ciw2, cib2, cew1, ceb1,
                                        cew2, ceb2, ws, out, use_atomic);
}

// Round 10
// 155.235 us; speedup vs baseline: 1.5346x; 1.0301x over previous
//
#include <hip/hip_runtime.h>

#define NBLK 1024   // encoder grid; partials live at ws[1024 .. 1024+NBLK*64)

// ws float layout:
#define WS_Z    0      // [0..127]   z                    (cross-block: AGENT)
#define WS_GHH  128    // [128..639] whh@hx + bhh         (same-block only)
#define WS_HNEW 640    // [640..767] h_new                (cross-block: AGENT)
#define WS_FEAT 840    // [840..903] feat post bias+relu  (cross-block: AGENT)
#define WS_BAR  992    // [992..999] spin-barrier counters (uint, zeroed by encoder)
#define WS_PART 1024   // encoder partials (or gmax[64] in atomic mode)

#define NTB 16         // tail blocks

typedef __attribute__((ext_vector_type(8))) short bf16x8;
typedef __attribute__((ext_vector_type(4))) float f32x4;

union U4 { unsigned int u[4]; bf16x8 v; };

static __device__ __forceinline__ unsigned int pack_bf16(float lo, float hi) {
    return (__float_as_uint(hi) & 0xFFFF0000u) | (__float_as_uint(lo) >> 16);
}

static __device__ __forceinline__ void ag_store(float* p, float v) {
    __hip_atomic_store(p, v, __ATOMIC_RELEASE, __HIP_MEMORY_SCOPE_AGENT);
}
static __device__ __forceinline__ float ag_load(const float* p) {
    return __hip_atomic_load(p, __ATOMIC_ACQUIRE, __HIP_MEMORY_SCOPE_AGENT);
}

// NTB-block spin barrier (device-scope; 16 blocks always co-resident)
static __device__ __forceinline__ void bar_sync(unsigned int* bar, int idx) {
    __syncthreads();
    if (threadIdx.x == 0) {
        __hip_atomic_fetch_add(&bar[idx], 1u, __ATOMIC_ACQ_REL, __HIP_MEMORY_SCOPE_AGENT);
        while (__hip_atomic_load(&bar[idx], __ATOMIC_ACQUIRE,
                                 __HIP_MEMORY_SCOPE_AGENT) < NTB) {}
    }
    __syncthreads();
}

// ---------------- atomic-mode prologue (only if ws too small) ----------------
__global__ __launch_bounds__(64) void prep_kernel(unsigned int* __restrict__ g)
{
    g[threadIdx.x & 63] = 0u;
}

// ---------- encoder: MLP 2->16->32->64 via MFMA, 32 points/wave/iter ----------
// Dual point-group: lanes q<2 own group A's L1 (k 0-7 / 8-15), q>=2 own group
// B's; one shfl_xor(32) builds B's fragment. 12 MFMAs per 32 points.
__global__ __launch_bounds__(256) void encoder_kernel(
    const float* __restrict__ x,
    const float* __restrict__ c1w, const float* __restrict__ c1b,
    const float* __restrict__ c2w, const float* __restrict__ c2b,
    const float* __restrict__ c3w,
    float* __restrict__ ws, int N, int use_atomic)
{
    __shared__ float sW1x[16], sW1y[16], sB1s[16];
    __shared__ float sW2[512], sB2[32];
    __shared__ float sW3[2048];
    __shared__ unsigned int sh2[4 * 544];   // per-wave: 2 groups x 16 rows x 17 dw
    __shared__ float wred[4 * 64];

    int t = threadIdx.x;
    if (blockIdx.x == 0 && t < 8) ((unsigned int*)ws)[WS_BAR + t] = 0u;
    if (t < 16) { sW1x[t] = c1w[2 * t]; sW1y[t] = c1w[2 * t + 1]; sB1s[t] = c1b[t]; }
    if (t < 32) sB2[t] = c2b[t];
    for (int i = t; i < 512; i += 256)  sW2[i] = c2w[i];
    for (int i = t; i < 2048; i += 256) sW3[i] = c3w[i];
    __syncthreads();

    const int lane = t & 63, wid = t >> 6;
    const int n16 = lane & 15, q = lane >> 4;
    const int g = q >> 1;             // point group (0=A, 1=B)
    const int kb = (q & 1) * 8;       // L1 k-base for this lane

    bf16x8 a2[2];                     // W2 (32x16), K zero-padded to 32
#pragma unroll
    for (int tt = 0; tt < 2; ++tt)
#pragma unroll
        for (int j = 0; j < 8; ++j) {
            int k = q * 8 + j;
            float w = (k < 16) ? sW2[(tt * 16 + n16) * 16 + k] : 0.0f;
            a2[tt][j] = (short)(__float_as_uint(w) >> 16);
        }
    bf16x8 a3[4];                     // W3 (64x32), K=32 exact
#pragma unroll
    for (int tt = 0; tt < 4; ++tt)
#pragma unroll
        for (int j = 0; j < 8; ++j) {
            float w = sW3[(tt * 16 + n16) * 32 + q * 8 + j];
            a3[tt][j] = (short)(__float_as_uint(w) >> 16);
        }
    float w1x[8], w1y[8], b1v[8];
#pragma unroll
    for (int j = 0; j < 8; ++j) {
        w1x[j] = sW1x[kb + j]; w1y[j] = sW1y[kb + j]; b1v[j] = sB1s[kb + j];
    }
    float b2a[4], b2b[4];
#pragma unroll
    for (int r = 0; r < 4; ++r) { b2a[r] = sB2[q * 4 + r]; b2b[r] = sB2[16 + q * 4 + r]; }

    float vmax[16];
#pragma unroll
    for (int i = 0; i < 16; ++i) vmax[i] = -INFINITY;

    unsigned int* hbA = sh2 + wid * 544;
    unsigned int* hbB = hbA + 272;
    const int WPG = NBLK * 4;
    const int gw = blockIdx.x * 4 + wid;
    const int niter = (N + WPG * 32 - 1) / (WPG * 32);

    int p = gw * 32 + g * 16 + n16; if (p >= N) p = N - 1;
    float px = x[3 + p], py = x[3 + N + p];

#pragma unroll 1
    for (int it = 0; it < niter; ++it) {
        float cpx = px, cpy = py;
        if (it + 1 < niter) {           // prefetch next tile's point
            int pn = (it + 1) * WPG * 32 + gw * 32 + g * 16 + n16;
            if (pn >= N) pn = N - 1;
            px = x[3 + pn]; py = x[3 + N + pn];
        }

        // ----- layer 1: 8 channels per lane (k = kb+j of its group's point) -----
        float h[8];
#pragma unroll
        for (int j = 0; j < 8; ++j)
            h[j] = fmaxf(fmaf(w1x[j], cpx, fmaf(w1y[j], cpy, b1v[j])), 0.f);
        unsigned int d0 = pack_bf16(h[0], h[1]), d1 = pack_bf16(h[2], h[3]);
        unsigned int d2 = pack_bf16(h[4], h[5]), d3 = pack_bf16(h[6], h[7]);
        unsigned int o0 = (unsigned int)__shfl_xor((int)d0, 32, 64);
        unsigned int o1 = (unsigned int)__shfl_xor((int)d1, 32, 64);
        unsigned int o2 = (unsigned int)__shfl_xor((int)d2, 32, 64);
        unsigned int o3 = (unsigned int)__shfl_xor((int)d3, 32, 64);
        U4 buA, buB;
        if (q < 2) {
            buA.u[0] = d0; buA.u[1] = d1; buA.u[2] = d2; buA.u[3] = d3;
            buB.u[0] = o0; buB.u[1] = o1; buB.u[2] = o2; buB.u[3] = o3;
        } else {
            buA.u[0] = buA.u[1] = buA.u[2] = buA.u[3] = 0u;   // K 16-31 pad
            buB.u[0] = buB.u[1] = buB.u[2] = buB.u[3] = 0u;
        }

        // ----- layer 2: 4 MFMAs (2 per group) -----
        f32x4 z4 = {0.f, 0.f, 0.f, 0.f};
        f32x4 aA0 = __builtin_amdgcn_mfma_f32_16x16x32_bf16(a2[0], buA.v, z4, 0, 0, 0);
        f32x4 aA1 = __builtin_amdgcn_mfma_f32_16x16x32_bf16(a2[1], buA.v, z4, 0, 0, 0);
        f32x4 aB0 = __builtin_amdgcn_mfma_f32_16x16x32_bf16(a2[0], buB.v, z4, 0, 0, 0);
        f32x4 aB1 = __builtin_amdgcn_mfma_f32_16x16x32_bf16(a2[1], buB.v, z4, 0, 0, 0);

        // ----- bias+relu, D->B layout via per-wave LDS transpose (both groups) -----
        unsigned int base = (unsigned int)(n16 * 17);
        hbA[base + 2 * q]     = pack_bf16(fmaxf(aA0[0] + b2a[0], 0.f),
                                          fmaxf(aA0[1] + b2a[1], 0.f));
        hbA[base + 2 * q + 1] = pack_bf16(fmaxf(aA0[2] + b2a[2], 0.f),
                                          fmaxf(aA0[3] + b2a[3], 0.f));
        hbA[base + 8 + 2 * q] = pack_bf16(fmaxf(aA1[0] + b2b[0], 0.f),
                                          fmaxf(aA1[1] + b2b[1], 0.f));
        hbA[base + 9 + 2 * q] = pack_bf16(fmaxf(aA1[2] + b2b[2], 0.f),
                                          fmaxf(aA1[3] + b2b[3], 0.f));
        hbB[base + 2 * q]     = pack_bf16(fmaxf(aB0[0] + b2a[0], 0.f),
                                          fmaxf(aB0[1] + b2a[1], 0.f));
        hbB[base + 2 * q + 1] = pack_bf16(fmaxf(aB0[2] + b2a[2], 0.f),
                                          fmaxf(aB0[3] + b2a[3], 0.f));
        hbB[base + 8 + 2 * q] = pack_bf16(fmaxf(aB1[0] + b2b[0], 0.f),
                                          fmaxf(aB1[1] + b2b[1], 0.f));
        hbB[base + 9 + 2 * q] = pack_bf16(fmaxf(aB1[2] + b2b[2], 0.f),
                                          fmaxf(aB1[3] + b2b[3], 0.f));
        __builtin_amdgcn_s_waitcnt(0xc07f);   // lgkmcnt(0): same-wave LDS RAW
        U4 ruA, ruB;
        ruA.u[0] = hbA[base + 4 * q];     ruA.u[1] = hbA[base + 4 * q + 1];
        ruA.u[2] = hbA[base + 4 * q + 2]; ruA.u[3] = hbA[base + 4 * q + 3];
        ruB.u[0] = hbB[base + 4 * q];     ruB.u[1] = hbB[base + 4 * q + 1];
        ruB.u[2] = hbB[base + 4 * q + 2]; ruB.u[3] = hbB[base + 4 * q + 3];

        // ----- layer 3: 8 MFMAs, raw output -> running max -----
        f32x4 oA0 = __builtin_amdgcn_mfma_f32_16x16x32_bf16(a3[0], ruA.v, z4, 0, 0, 0);
        f32x4 oA1 = __builtin_amdgcn_mfma_f32_16x16x32_bf16(a3[1], ruA.v, z4, 0, 0, 0);
        f32x4 oA2 = __builtin_amdgcn_mfma_f32_16x16x32_bf16(a3[2], ruA.v, z4, 0, 0, 0);
        f32x4 oA3 = __builtin_amdgcn_mfma_f32_16x16x32_bf16(a3[3], ruA.v, z4, 0, 0, 0);
        f32x4 oB0 = __builtin_amdgcn_mfma_f32_16x16x32_bf16(a3[0], ruB.v, z4, 0, 0, 0);
        f32x4 oB1 = __builtin_amdgcn_mfma_f32_16x16x32_bf16(a3[1], ruB.v, z4, 0, 0, 0);
        f32x4 oB2 = __builtin_amdgcn_mfma_f32_16x16x32_bf16(a3[2], ruB.v, z4, 0, 0, 0);
        f32x4 oB3 = __builtin_amdgcn_mfma_f32_16x16x32_bf16(a3[3], ruB.v, z4, 0, 0, 0);
#pragma unroll
        for (int r = 0; r < 4; ++r) {
            vmax[r]      = fmaxf(vmax[r],      fmaxf(oA0[r], oB0[r]));
            vmax[4 + r]  = fmaxf(vmax[4 + r],  fmaxf(oA1[r], oB1[r]));
            vmax[8 + r]  = fmaxf(vmax[8 + r],  fmaxf(oA2[r], oB2[r]));
            vmax[12 + r] = fmaxf(vmax[12 + r], fmaxf(oA3[r], oB3[r]));
        }
    }

    // reduce across the 16 point-lanes (n16 dimension)
#pragma unroll
    for (int i = 0; i < 16; ++i) {
        float v = vmax[i];
        v = fmaxf(v, __shfl_xor(v, 1, 64));
        v = fmaxf(v, __shfl_xor(v, 2, 64));
        v = fmaxf(v, __shfl_xor(v, 4, 64));
        v = fmaxf(v, __shfl_xor(v, 8, 64));
        vmax[i] = v;
    }
    if (n16 == 0) {
#pragma unroll
        for (int tt = 0; tt < 4; ++tt)
#pragma unroll
            for (int r = 0; r < 4; ++r)
                wred[wid * 64 + tt * 16 + q * 4 + r] = vmax[tt * 4 + r];
    }
    __syncthreads();
    if (t < 64) {
        float m = fmaxf(fmaxf(wred[t], wred[64 + t]),
                        fmaxf(wred[128 + t], wred[192 + t]));
        if (use_atomic) {
            unsigned int b = __float_as_uint(m);
            unsigned int e = (b & 0x80000000u) ? ~b : (b | 0x80000000u);
            atomicMax((unsigned int*)ws + WS_PART + t, e);
        } else {
            ws[WS_PART + blockIdx.x * 64 + t] = m;
        }
    }
}

// ---------- fused tail: 16 blocks, 3 spin barriers, register prefetch ----------
__global__ __launch_bounds__(256) void tail_fused(
    const float* __restrict__ x,   const float* __restrict__ hx,
    const float* __restrict__ cx,  const float* __restrict__ c3b,
    const float* __restrict__ fcw, const float* __restrict__ fcb,
    const float* __restrict__ o1w, const float* __restrict__ o1b,
    const float* __restrict__ o2w, const float* __restrict__ o2b,
    const float* __restrict__ pw,  const float* __restrict__ pb,
    const float* __restrict__ wih, const float* __restrict__ whh,
    const float* __restrict__ bih, const float* __restrict__ bhh,
    const float* __restrict__ q1w, const float* __restrict__ q1b,
    const float* __restrict__ q2w, const float* __restrict__ q2b,
    const float* __restrict__ aw1, const float* __restrict__ ab1,
    const float* __restrict__ aw2, const float* __restrict__ ab2,
    const float* __restrict__ ciw1, const float* __restrict__ cib1,
    const float* __restrict__ ciw2, const float* __restrict__ cib2,
    const float* __restrict__ cew1, const float* __restrict__ ceb1,
    const float* __restrict__ cew2, const float* __restrict__ ceb2,
    float* __restrict__ ws, float* __restrict__ out, int use_atomic)
{
    const int b = blockIdx.x, t = threadIdx.x;
    unsigned int* bar = (unsigned int*)ws + WS_BAR;
    __shared__ float shx[128], inL[72], zL[128], lg[32], hnL[128];
    __shared__ float featL[64], obsL[64], zp1L[64], zp2L[64];
    __shared__ float sig8L[8], odomL[3], poseL[8];
    __shared__ float a1s[16], cih[16], ceh[16], logits[5];

    // ---- prefetch (issued immediately; waited at first use) ----
    const int rl = t >> 3, sub8 = t & 7;
    const int gr = (rl >> 3) * 128 + b * 8 + (rl & 7);   // gate row
    const float4* wih4 = (const float4*)(wih + (size_t)gr * 128) + sub8 * 4;
    float4 wr0 = wih4[0], wr1 = wih4[1], wr2 = wih4[2], wr3 = wih4[3]; // used P2

    float4 fw0, fw1, fw2, fw3;                       // fcw row (b0, used P1)
    float4 pv0, pv1, pv2, pv3, pv4, pv5, pv6, pv7, pv8; // pw row (b0, used P1)
    if (b == 0) {
        const float4* f4 = (const float4*)(fcw + (size_t)(t >> 2) * 64) + (t & 3) * 4;
        fw0 = f4[0]; fw1 = f4[1]; fw2 = f4[2]; fw3 = f4[3];
        const float4* p4 = (const float4*)(pw + (size_t)(t >> 1) * 72) + (t & 1) * 9;
        pv0 = p4[0]; pv1 = p4[1]; pv2 = p4[2]; pv3 = p4[3]; pv4 = p4[4];
        pv5 = p4[5]; pv6 = p4[6]; pv7 = p4[7]; pv8 = p4[8];
    }

    // ---- P0: ghh rows (all) + feat reduce (all) + pose (b0) ----
    if (t < 128) shx[t] = hx[t];
    __syncthreads();
    {
        const float4* w4 = (const float4*)(whh + (size_t)gr * 128) + sub8 * 4;
        float s = 0.0f;
#pragma unroll
        for (int j = 0; j < 4; j++) {
            float4 w = w4[j];
            int k = sub8 * 16 + 4 * j;
            s = fmaf(w.x, shx[k], fmaf(w.y, shx[k + 1],
                fmaf(w.z, shx[k + 2], fmaf(w.w, shx[k + 3], s))));
        }
        s += __shfl_xor(s, 1, 64); s += __shfl_xor(s, 2, 64); s += __shfl_xor(s, 4, 64);
        if (sub8 == 0) ws[WS_GHH + gr] = bhh[gr] + s;   // same-block consumer (P2)
    }
    if (!use_atomic) {
        int w = t >> 6, lane = t & 63;
        int c = b * 4 + w;
        float m = -INFINITY;
        const float* part = ws + WS_PART;
#pragma unroll 4
        for (int j = 0; j < NBLK / 64; j++)
            m = fmaxf(m, part[(lane * (NBLK / 64) + j) * 64 + c]);
#pragma unroll
        for (int off = 32; off > 0; off >>= 1)
            m = fmaxf(m, __shfl_xor(m, off, 64));
        if (lane == 0) ag_store(&ws[WS_FEAT + c], fmaxf(m + c3b[c], 0.0f));
    } else if (b == 0 && t >= 128 && t < 192) {
        int c = t - 128;
        unsigned int u = ((unsigned int*)ws)[WS_PART + c];
        unsigned int bb = (u & 0x80000000u) ? (u ^ 0x80000000u) : ~u;
        ag_store(&ws[WS_FEAT + c], fmaxf(__uint_as_float(bb) + c3b[c], 0.0f));
    }
    if (b == 0) {
        if (t < 3) odomL[t] = x[t];
        __syncthreads();
        if (t < 8) {
            float s = o1b[t];
            for (int k = 0; k < 3; k++) s = fmaf(o1w[t * 3 + k], odomL[k], s);
            sig8L[t] = 1.0f / (1.0f + expf(-s));
        }
        __syncthreads();
        if (t < 8) {
            float s = o2b[t];
            for (int k = 0; k < 8; k++) s = fmaf(o2w[t * 8 + k], sig8L[k], s);
            float pv = fmaxf(s, 0.0f);
            poseL[t] = pv;
            out[263 + t] = pv;
        }
    }
    bar_sync(bar, 0);

    // ---- P1 (b0 only): obs = fcw@feat+fcb ; z = relu(pw@[obs;pose]+pb) ----
    if (b == 0) {
        if (t < 64) featL[t] = ag_load(&ws[WS_FEAT + t]);
        __syncthreads();
        {   // obs: 64 rows x 4 sub-threads (weights in regs)
            int row = t >> 2, sub = t & 3;
            int k = sub * 16;
            float s;
            s = fmaf(fw0.x, featL[k],      fmaf(fw0.y, featL[k + 1],
                fmaf(fw0.z, featL[k + 2],  fmaf(fw0.w, featL[k + 3], 0.0f))));
            s = fmaf(fw1.x, featL[k + 4],  fmaf(fw1.y, featL[k + 5],
                fmaf(fw1.z, featL[k + 6],  fmaf(fw1.w, featL[k + 7], s))));
            s = fmaf(fw2.x, featL[k + 8],  fmaf(fw2.y, featL[k + 9],
                fmaf(fw2.z, featL[k + 10], fmaf(fw2.w, featL[k + 11], s))));
            s = fmaf(fw3.x, featL[k + 12], fmaf(fw3.y, featL[k + 13],
                fmaf(fw3.z, featL[k + 14], fmaf(fw3.w, featL[k + 15], s))));
            s += __shfl_xor(s, 1, 64); s += __shfl_xor(s, 2, 64);
            if (sub == 0) obsL[row] = s + fcb[row];
        }
        __syncthreads();
        if (t < 64) inL[t] = obsL[t];
        else if (t < 72) inL[t] = poseL[t - 64];
        __syncthreads();
        {   // z: 128 rows x 2 sub-threads (weights in regs)
            int row = t >> 1, sub = t & 1;
            int k = sub * 36;
            float s = 0.0f;
            float4 pv[9] = {pv0, pv1, pv2, pv3, pv4, pv5, pv6, pv7, pv8};
#pragma unroll
            for (int j = 0; j < 9; j++) {
                s = fmaf(pv[j].x, inL[k + 4 * j],     fmaf(pv[j].y, inL[k + 4 * j + 1],
                    fmaf(pv[j].z, inL[k + 4 * j + 2], fmaf(pv[j].w, inL[k + 4 * j + 3], s))));
            }
            s += __shfl_xor(s, 1, 64);
            if (sub == 0) ag_store(&ws[WS_Z + row], fmaxf(s + pb[row], 0.0f));
        }
    }
    bar_sync(bar, 1);

    // ---- P2 (all): gates from prefetched wih regs; LSTM update (8 cells/block) ----
    if (t < 128) zL[t] = ag_load(&ws[WS_Z + t]);
    __syncthreads();
    {
        int k = sub8 * 16;
        float s;
        s = fmaf(wr0.x, zL[k],      fmaf(wr0.y, zL[k + 1],
            fmaf(wr0.z, zL[k + 2],  fmaf(wr0.w, zL[k + 3], 0.0f))));
        s = fmaf(wr1.x, zL[k + 4],  fmaf(wr1.y, zL[k + 5],
            fmaf(wr1.z, zL[k + 6],  fmaf(wr1.w, zL[k + 7], s))));
        s = fmaf(wr2.x, zL[k + 8],  fmaf(wr2.y, zL[k + 9],
            fmaf(wr2.z, zL[k + 10], fmaf(wr2.w, zL[k + 11], s))));
        s = fmaf(wr3.x, zL[k + 12], fmaf(wr3.y, zL[k + 13],
            fmaf(wr3.z, zL[k + 14], fmaf(wr3.w, zL[k + 15], s))));
        s += __shfl_xor(s, 1, 64); s += __shfl_xor(s, 2, 64); s += __shfl_xor(s, 4, 64);
        if (sub8 == 0) lg[rl] = ws[WS_GHH + gr] + bih[gr] + s;
    }
    __syncthreads();
    if (t < 8) {
        int c = b * 8 + t;
        float gI = lg[t], gF = lg[8 + t], gG = lg[16 + t], gO = lg[24 + t];
        float ig = 1.0f / (1.0f + expf(-gI));
        float fg = 1.0f / (1.0f + expf(-gF));
        float gg = tanhf(gG);
        float og = 1.0f / (1.0f + expf(-gO));
        float cn = fg * cx[c] + ig * gg;
        float hn = og * tanhf(cn);
        out[7 + c] = hn;
        out[135 + c] = cn;
        ag_store(&ws[WS_HNEW + c], hn);
    }
    // b0: issue q1w/q2w prefetch now (used after bar2)
    float4 q1r0, q1r1, q1r2, q1r3, q1r4, q1r5, q1r6, q1r7;
    float4 q2r0, q2r1, q2r2, q2r3;
    if (b == 0) {
        const float4* a4 = (const float4*)(q1w + (size_t)(t >> 2) * 128) + (t & 3) * 8;
        q1r0 = a4[0]; q1r1 = a4[1]; q1r2 = a4[2]; q1r3 = a4[3];
        q1r4 = a4[4]; q1r5 = a4[5]; q1r6 = a4[6]; q1r7 = a4[7];
        const float4* b4 = (const float4*)(q2w + (size_t)(t >> 2) * 64) + (t & 3) * 4;
        q2r0 = b4[0]; q2r1 = b4[1]; q2r2 = b4[2]; q2r3 = b4[3];
    }
    bar_sync(bar, 2);

    // ---- P3 (b0 only): zp1, zp2, heads, softmax ----
    if (b == 0) {
        if (t < 128) hnL[t] = ag_load(&ws[WS_HNEW + t]);
        __syncthreads();
        {   // zp1: 64 rows x 4 sub-threads, q1w from regs
            int row = t >> 2, sub = t & 3;
            int k = sub * 32;
            float4 qr[8] = {q1r0, q1r1, q1r2, q1r3, q1r4, q1r5, q1r6, q1r7};
            float s = 0.0f;
#pragma unroll
            for (int j = 0; j < 8; j++) {
                s = fmaf(qr[j].x, hnL[k + 4 * j],     fmaf(qr[j].y, hnL[k + 4 * j + 1],
                    fmaf(qr[j].z, hnL[k + 4 * j + 2], fmaf(qr[j].w, hnL[k + 4 * j + 3], s))));
            }
            s += __shfl_xor(s, 1, 64); s += __shfl_xor(s, 2, 64);
            if (sub == 0) zp1L[row] = fmaxf(s + q1b[row], 0.0f);
        }
        __syncthreads();
        {   // zp2: 64 rows x 4 sub-threads, q2w from regs
            int row = t >> 2, sub = t & 3;
            int k = sub * 16;
            float4 qr[4] = {q2r0, q2r1, q2r2, q2r3};
            float s = 0.0f;
#pragma unroll
            for (int j = 0; j < 4; j++) {
                s = fmaf(qr[j].x, zp1L[k + 4 * j],     fmaf(qr[j].y, zp1L[k + 4 * j + 1],
                    fmaf(qr[j].z, zp1L[k + 4 * j + 2], fmaf(qr[j].w, zp1L[k + 4 * j + 3], s))));
            }
            s += __shfl_xor(s, 1, 64); s += __shfl_xor(s, 2, 64);
            if (sub == 0) zp2L[row] = fmaxf(s + q2b[row], 0.0f);
        }
        __syncthreads();
        if (t < 16) {
            float s = ab1[t];
            for (int k = 0; k < 64; k++) s = fmaf(aw1[t * 64 + k], zp2L[k], s);
            a1s[t] = fmaxf(s, 0.0f);
        } else if (t < 32) {
            int r = t - 16;
            float s = cib1[r];
            for (int k = 0; k < 64; k++) s = fmaf(ciw1[r * 64 + k], zp2L[k], s);
            cih[r] = fmaxf(s, 0.0f);
        } else if (t < 48) {
            int r = t - 32;
            float s = ceb1[r];
            for (int k = 0; k < 64; k++) s = fmaf(cew1[r * 64 + k], zp2L[k], s);
            ceh[r] = fmaxf(s, 0.0f);
        }
        __syncthreads();
        if (t < 5) {
            float s = ab2[t];
            for (int k = 0; k < 16; k++) s = fmaf(aw2[t * 16 + k], a1s[k], s);
            logits[t] = s;
        } else if (t == 5) {
            float s = cib2[0];
            for (int k = 0; k < 16; k++) s = fmaf(ciw2[k], cih[k], s);
            out[5] = s;
        } else if (t == 6) {
            float s = ceb2[0];
            for (int k = 0; k < 16; k++) s = fmaf(cew2[k], ceh[k], s);
            out[6] = s;
        }
        __syncthreads();
        if (t == 0) {
            float m = logits[0];
            for (int i = 1; i < 5; i++) m = fmaxf(m, logits[i]);
            float e[5], s = 0.0f;
            for (int i = 0; i < 5; i++) { e[i] = expf(logits[i] - m); s += e[i]; }
            for (int i = 0; i < 5; i++) out[i] = e[i] / s;
        }
    }
}

extern "C" void kernel_launch(void* const* d_in, const int* in_sizes, int n_in,
                              void* d_out, int out_size, void* d_ws, size_t ws_size,
                              hipStream_t stream)
{
    const float* x    = (const float*)d_in[0];
    const float* hx   = (const float*)d_in[1];
    const float* cx   = (const float*)d_in[2];
    const float* c1w  = (const float*)d_in[3];
    const float* c1b  = (const float*)d_in[4];
    const float* c2w  = (const float*)d_in[5];
    const float* c2b  = (const float*)d_in[6];
    const float* c3w  = (const float*)d_in[7];
    const float* c3b  = (const float*)d_in[8];
    const float* fcw  = (const float*)d_in[9];
    const float* fcb  = (const float*)d_in[10];
    const float* o1w  = (const float*)d_in[11];
    const float* o1b  = (const float*)d_in[12];
    const float* o2w  = (const float*)d_in[13];
    const float* o2b  = (const float*)d_in[14];
    const float* pw   = (const float*)d_in[15];
    const float* pb   = (const float*)d_in[16];
    const float* wih  = (const float*)d_in[17];
    const float* whh  = (const float*)d_in[18];
    const float* bih  = (const float*)d_in[19];
    const float* bhh  = (const float*)d_in[20];
    const float* q1w  = (const float*)d_in[21];
    const float* q1b  = (const float*)d_in[22];
    const float* q2w  = (const float*)d_in[23];
    const float* q2b  = (const float*)d_in[24];
    const float* aw1  = (const float*)d_in[25];
    const float* ab1  = (const float*)d_in[26];
    const float* aw2  = (const float*)d_in[27];
    const float* ab2  = (const float*)d_in[28];
    const float* ciw1 = (const float*)d_in[29];
    const float* cib1 = (const float*)d_in[30];
    const float* ciw2 = (const float*)d_in[31];
    const float* cib2 = (const float*)d_in[32];
    const float* cew1 = (const float*)d_in[33];
    const float* ceb1 = (const float*)d_in[34];
    const float* cew2 = (const float*)d_in[35];
    const float* ceb2 = (const float*)d_in[36];

    int N = (in_sizes[0] - 3) / 2;
    size_t need = (size_t)(1024 + NBLK * 64) * 4;
    int use_atomic = (ws_size < need) ? 1 : 0;
    float* ws = (float*)d_ws;
    float* out = (float*)d_out;

    if (use_atomic)
        prep_kernel<<<1, 64, 0, stream>>>((unsigned int*)d_ws + WS_PART);
    encoder_kernel<<<NBLK, 256, 0, stream>>>(x, c1w, c1b, c2w, c2b, c3w,
                                             ws, N, use_atomic);
    tail_fused<<<NTB, 256, 0, stream>>>(x, hx, cx, c3b, fcw, fcb, o1w, o1b,
                                        o2w, o2b, pw, pb, wih, whh, bih, bhh,
                                        q1w, q1b, q2w, q2b, aw1, ab1, aw2, ab2,
                                        ciw1, cib1, ciw2, cib2, cew1, ceb1,
                                        cew2, ceb2, ws, out, use_atomic);
}